// Round 4
// baseline (373.171 us; speedup 1.0000x reference)
//
#include <hip/hip_runtime.h>
#include <hip/hip_bf16.h>
#include <math.h>
#include <stdint.h>

#define B_ 2
#define S_ 2048
#define E_ 2048
#define H_ 16
#define NOPE_ 64
#define ROPE_ 32
#define V_ 64
#define KVR_ 256
#define QKD_ 96
#define SCALE_ 0.10206207261596577f  /* 96^-0.5 */

typedef __hip_bfloat16 bf16;
typedef __attribute__((ext_vector_type(8))) short short8;
typedef __attribute__((ext_vector_type(4))) short short4v;
typedef __attribute__((ext_vector_type(4))) float floatx4;

__device__ __forceinline__ float bf2f(bf16 v) { return __bfloat162float(v); }
__device__ __forceinline__ float s2f(short v) {
    bf16 h = *reinterpret_cast<bf16*>(&v);
    return __bfloat162float(h);
}
__device__ __forceinline__ short f2bf_s(float f) {
    bf16 h = __float2bfloat16(f);
    return *reinterpret_cast<short*>(&h);
}
__device__ __forceinline__ void store_c(float* C, size_t i, float v) { C[i] = v; }
__device__ __forceinline__ void store_c(bf16* C, size_t i, float v) { C[i] = __float2bfloat16(v); }

// async 16B global -> LDS. Proper addrspacecasts (NO integer truncation — flat LDS
// addresses are aperture-based; C-style cast emits the correct addrspacecast).
__device__ __forceinline__ void g2l16(const bf16* g, bf16* l) {
    __builtin_amdgcn_global_load_lds(
        (const __attribute__((address_space(1))) void*)g,
        (__attribute__((address_space(3))) void*)l,
        16, 0, 0);
}

// ---------------- fused fp32 -> bf16 conversions (hs, wq, wo, wkv_b, wkv_a-pad) ----------
#define CV_N0 1048576              /* hs:    4096*2048/8 */
#define CV_N1 (CV_N0 + 393216)     /* wq:    1536*2048/8 */
#define CV_N2 (CV_N1 + 262144)     /* wo:    2048*1024/8 */
#define CV_N3 (CV_N2 + 65536)      /* wkv_b: 2048*256/8  */
#define CV_N4 (CV_N3 + 98304)      /* wkva_pad: 384*2048/8 */
__global__ __launch_bounds__(256) void conv_fused_kernel(const float* __restrict__ hs,
                                                         const float* __restrict__ wq,
                                                         const float* __restrict__ wo,
                                                         const float* __restrict__ wkv_b,
                                                         const float* __restrict__ wkv_a,
                                                         bf16* __restrict__ hs_bf,
                                                         bf16* __restrict__ wq_bf,
                                                         bf16* __restrict__ wo_bf,
                                                         bf16* __restrict__ wkvb_bf,
                                                         bf16* __restrict__ wkva_pad) {
    int i = blockIdx.x * 256 + threadIdx.x;
    const float* src;
    bf16* dst;
    int j;
    if (i < CV_N0)      { src = hs;    dst = hs_bf;   j = i; }
    else if (i < CV_N1) { src = wq;    dst = wq_bf;   j = i - CV_N0; }
    else if (i < CV_N2) { src = wo;    dst = wo_bf;   j = i - CV_N1; }
    else if (i < CV_N3) { src = wkv_b; dst = wkvb_bf; j = i - CV_N2; }
    else if (i < CV_N4) {
        j = i - CV_N3;
        int row = j >> 8;
        short8 r;
        if (row < 288) {
            float4 a = ((const float4*)wkv_a)[2 * j];
            float4 b = ((const float4*)wkv_a)[2 * j + 1];
            r[0] = f2bf_s(a.x); r[1] = f2bf_s(a.y); r[2] = f2bf_s(a.z); r[3] = f2bf_s(a.w);
            r[4] = f2bf_s(b.x); r[5] = f2bf_s(b.y); r[6] = f2bf_s(b.z); r[7] = f2bf_s(b.w);
        } else {
            for (int k = 0; k < 8; ++k) r[k] = 0;
        }
        ((short8*)wkva_pad)[j] = r;
        return;
    } else return;
    float4 a = ((const float4*)src)[2 * j];
    float4 b = ((const float4*)src)[2 * j + 1];
    short8 r;
    r[0] = f2bf_s(a.x); r[1] = f2bf_s(a.y); r[2] = f2bf_s(a.z); r[3] = f2bf_s(a.w);
    r[4] = f2bf_s(b.x); r[5] = f2bf_s(b.y); r[6] = f2bf_s(b.z); r[7] = f2bf_s(b.w);
    ((short8*)dst)[j] = r;
}

// ---------------- wkvbT[h][c][d] = bf16(wkv_b[h*128+d][c]), d<64 ----------------
__global__ __launch_bounds__(256) void transpose_wkvbT_kernel(const float* __restrict__ wkv_b,
                                                              bf16* __restrict__ wkvbT) {
    int h = blockIdx.x, c = threadIdx.x;
#pragma unroll
    for (int d0 = 0; d0 < 64; d0 += 8) {
        short8 v;
#pragma unroll
        for (int j = 0; j < 8; ++j) v[j] = f2bf_s(wkv_b[(size_t)(h * 128 + d0 + j) * 256 + c]);
        *(short8*)(void*)&wkvbT[((size_t)h * 256 + c) * 64 + d0] = v;
    }
}

// ---------------- bf16 MFMA GEMM (m97-style): C(M,N) = A(M,K) @ B(N,K)^T ----------------
template <typename TC>
__global__ __launch_bounds__(256, 2) void gemm_bt_lds(const bf16* __restrict__ A,
                                                      const bf16* __restrict__ Bm,
                                                      TC* __restrict__ C,
                                                      int M, int N, int K) {
    __shared__ bf16 Asf[128 * 32];
    __shared__ bf16 Bsf[128 * 32];
    int tid = threadIdx.x;
    int lane = tid & 63, w = tid >> 6;
    int q4 = lane >> 4, c16 = lane & 15;
    int wr = w >> 1, wc = w & 1;
    int m0 = blockIdx.y * 128, n0 = blockIdx.x * 128;
    floatx4 acc[4][4];
#pragma unroll
    for (int mi = 0; mi < 4; ++mi)
#pragma unroll
        for (int ni = 0; ni < 4; ++ni) acc[mi][ni] = (floatx4){0.f, 0.f, 0.f, 0.f};

    for (int k0 = 0; k0 < K; k0 += 32) {
        __syncthreads();
#pragma unroll
        for (int i = 0; i < 2; ++i) {
            int c = (w << 6) + lane + i * 256;
            int row = c >> 2, kc = c & 3;
            g2l16(&A[(size_t)(m0 + row) * K + k0 + kc * 8], &Asf[c * 8]);
            g2l16(&Bm[(size_t)(n0 + row) * K + k0 + kc * 8], &Bsf[c * 8]);
        }
        __syncthreads();
        short8 af[4], bfr[4];
#pragma unroll
        for (int mi = 0; mi < 4; ++mi)
            af[mi] = *(const short8*)(const void*)&Asf[(wr * 64 + mi * 16 + c16) * 32 + q4 * 8];
#pragma unroll
        for (int ni = 0; ni < 4; ++ni)
            bfr[ni] = *(const short8*)(const void*)&Bsf[(wc * 64 + ni * 16 + c16) * 32 + q4 * 8];
#pragma unroll
        for (int mi = 0; mi < 4; ++mi)
#pragma unroll
            for (int ni = 0; ni < 4; ++ni)
                acc[mi][ni] = __builtin_amdgcn_mfma_f32_16x16x32_bf16(af[mi], bfr[ni], acc[mi][ni], 0, 0, 0);
    }
#pragma unroll
    for (int mi = 0; mi < 4; ++mi)
#pragma unroll
        for (int ni = 0; ni < 4; ++ni)
#pragma unroll
            for (int r = 0; r < 4; ++r) {
                int row = m0 + wr * 64 + mi * 16 + q4 * 4 + r;
                int col = n0 + wc * 64 + ni * 16 + c16;
                store_c(C, (size_t)row * N + col, acc[mi][ni][r]);
            }
}

// ---------------- fused projection GEMM: q (bf16 out, N=1536) + kvraw (f32 out, N=384) ---
__global__ __launch_bounds__(256, 2) void gemm_qkv_fused(const bf16* __restrict__ A,
                                                         const bf16* __restrict__ Bq,
                                                         const bf16* __restrict__ Bkv,
                                                         bf16* __restrict__ Cq,
                                                         float* __restrict__ Ckv,
                                                         int K) {
    __shared__ bf16 Asf[128 * 32];
    __shared__ bf16 Bsf[128 * 32];
    int tid = threadIdx.x;
    int lane = tid & 63, w = tid >> 6;
    int q4 = lane >> 4, c16 = lane & 15;
    int wr = w >> 1, wc = w & 1;
    int bx = blockIdx.x;
    bool isq = bx < 12;
    const bf16* Bm = isq ? Bq : Bkv;
    int n0 = isq ? bx * 128 : (bx - 12) * 128;
    int m0 = blockIdx.y * 128;
    floatx4 acc[4][4];
#pragma unroll
    for (int mi = 0; mi < 4; ++mi)
#pragma unroll
        for (int ni = 0; ni < 4; ++ni) acc[mi][ni] = (floatx4){0.f, 0.f, 0.f, 0.f};

    for (int k0 = 0; k0 < K; k0 += 32) {
        __syncthreads();
#pragma unroll
        for (int i = 0; i < 2; ++i) {
            int c = (w << 6) + lane + i * 256;
            int row = c >> 2, kc = c & 3;
            g2l16(&A[(size_t)(m0 + row) * K + k0 + kc * 8], &Asf[c * 8]);
            g2l16(&Bm[(size_t)(n0 + row) * K + k0 + kc * 8], &Bsf[c * 8]);
        }
        __syncthreads();
        short8 af[4], bfr[4];
#pragma unroll
        for (int mi = 0; mi < 4; ++mi)
            af[mi] = *(const short8*)(const void*)&Asf[(wr * 64 + mi * 16 + c16) * 32 + q4 * 8];
#pragma unroll
        for (int ni = 0; ni < 4; ++ni)
            bfr[ni] = *(const short8*)(const void*)&Bsf[(wc * 64 + ni * 16 + c16) * 32 + q4 * 8];
#pragma unroll
        for (int mi = 0; mi < 4; ++mi)
#pragma unroll
            for (int ni = 0; ni < 4; ++ni)
                acc[mi][ni] = __builtin_amdgcn_mfma_f32_16x16x32_bf16(af[mi], bfr[ni], acc[mi][ni], 0, 0, 0);
    }
#pragma unroll
    for (int mi = 0; mi < 4; ++mi)
#pragma unroll
        for (int ni = 0; ni < 4; ++ni)
#pragma unroll
            for (int r = 0; r < 4; ++r) {
                int row = m0 + wr * 64 + mi * 16 + q4 * 4 + r;
                int col = n0 + wc * 64 + ni * 16 + c16;
                if (isq)
                    Cq[(size_t)row * 1536 + col] = __float2bfloat16(acc[mi][ni][r]);
                else
                    Ckv[(size_t)row * 384 + col] = acc[mi][ni][r];
            }
}

// ---------------- small batched bf16 MFMA GEMM (64x64 tiles, global_load_lds) -------------
template <typename TC>
__global__ __launch_bounds__(256, 4) void gemm64_lds(const bf16* __restrict__ A, int lda, int aoffz,
                                                     const bf16* __restrict__ Bm, int ldb, int boffz,
                                                     TC* __restrict__ C, int ldc, int coffz,
                                                     int K, float scale) {
    int z = blockIdx.z;
    A += (size_t)z * aoffz;
    Bm += (size_t)z * boffz;
    C += (size_t)z * coffz;
    __shared__ bf16 Asf[64 * 32];
    __shared__ bf16 Bsf[64 * 32];
    int tid = threadIdx.x;
    int lane = tid & 63, w = tid >> 6;
    int q4 = lane >> 4, c16 = lane & 15;
    int m0 = blockIdx.y * 64, n0 = blockIdx.x * 64;
    floatx4 acc[4];
#pragma unroll
    for (int ni = 0; ni < 4; ++ni) acc[ni] = (floatx4){0.f, 0.f, 0.f, 0.f};
    int row = tid >> 2, kc = tid & 3;
    for (int k0 = 0; k0 < K; k0 += 32) {
        __syncthreads();
        g2l16(&A[(size_t)(m0 + row) * lda + k0 + kc * 8], &Asf[tid * 8]);
        g2l16(&Bm[(size_t)(n0 + row) * ldb + k0 + kc * 8], &Bsf[tid * 8]);
        __syncthreads();
        short8 af = *(const short8*)(const void*)&Asf[(w * 16 + c16) * 32 + q4 * 8];
#pragma unroll
        for (int ni = 0; ni < 4; ++ni) {
            short8 bfr = *(const short8*)(const void*)&Bsf[(ni * 16 + c16) * 32 + q4 * 8];
            acc[ni] = __builtin_amdgcn_mfma_f32_16x16x32_bf16(af, bfr, acc[ni], 0, 0, 0);
        }
    }
#pragma unroll
    for (int ni = 0; ni < 4; ++ni)
#pragma unroll
        for (int rr = 0; rr < 4; ++rr)
            store_c(C, (size_t)(m0 + w * 16 + q4 * 4 + rr) * ldc + n0 + ni * 16 + c16,
                    acc[ni][rr] * scale);
}

// ---------------- LayerNorm(kv_c) + RoPE(k_pe); input stride 384 ----------------
__global__ __launch_bounds__(256) void ln_rope_kernel(const float* __restrict__ kvraw,
                                                      const float* __restrict__ g,
                                                      const float* __restrict__ bta,
                                                      float* __restrict__ kv_c,
                                                      float* __restrict__ kpe) {
    int r = blockIdx.x;
    int tid = threadIdx.x;
    int lane = tid & 63, w = tid >> 6;
    float x = kvraw[(size_t)r * 384 + tid];
    float v1 = x, v2 = x * x;
#pragma unroll
    for (int o = 32; o; o >>= 1) { v1 += __shfl_down(v1, o); v2 += __shfl_down(v2, o); }
    __shared__ float s1[4], s2[4], stats[2];
    if (lane == 0) { s1[w] = v1; s2[w] = v2; }
    __syncthreads();
    if (tid == 0) {
        float S1 = s1[0] + s1[1] + s1[2] + s1[3];
        float S2 = s2[0] + s2[1] + s2[2] + s2[3];
        float mean = S1 / 256.0f;
        float var = S2 / 256.0f - mean * mean;
        stats[0] = mean;
        stats[1] = rsqrtf(var + 1e-5f);
    }
    __syncthreads();
    float y = (x - stats[0]) * stats[1] * g[tid] + bta[tid];
    kv_c[(size_t)r * 256 + tid] = y;
    if (tid < 16) {
        int j = tid;
        int s = r & (S_ - 1);
        float freq = expf(-(float)(2 * j) * 0.28782313662425572f);  // ln(1e4)/32
        float ang = (float)s * freq;
        float c = cosf(ang), sn = sinf(ang);
        float x0 = kvraw[(size_t)r * 384 + 256 + 2 * j];
        float x1 = kvraw[(size_t)r * 384 + 256 + 2 * j + 1];
        kpe[(size_t)r * 32 + 2 * j]     = x0 * c - x1 * sn;
        kpe[(size_t)r * 32 + 2 * j + 1] = x0 * sn + x1 * c;
    }
}

// ---------------- C2 / P2 ----------------
__global__ __launch_bounds__(64) void c2p2_kernel(const float* __restrict__ fcw_c,
                                                  const float* __restrict__ fcb_c,
                                                  const float* __restrict__ fcw_p,
                                                  const float* __restrict__ fcb_p,
                                                  float* __restrict__ C2,
                                                  float* __restrict__ P2) {
    int t = blockIdx.x;
    int k = threadIdx.x;
    __shared__ float Crow[256], Prow[256];
    for (int i = k; i < 128; i += 64) {
        float div = expf(-(float)i * 0.07195578415606393f);  // ln(1e4)/128
        float ap = (float)t * div;
        Prow[2 * i]     = sinf(ap);
        Prow[2 * i + 1] = cosf(ap);
        float ac = (float)(t >> 1) * div;
        Crow[2 * i]     = sinf(ac);
        Crow[2 * i + 1] = cosf(ac);
    }
    __syncthreads();
    float sc = fcb_c[k], sp = fcb_p[k];
    for (int c = 0; c < 256; ++c) {
        sc += Crow[c] * fcw_c[(size_t)k * 256 + c];
        sp += Prow[c] * fcw_p[(size_t)k * 256 + c];
    }
    C2[(size_t)t * 64 + k] = sc;
    P2[(size_t)t * 64 + k] = sp;
}

__global__ __launch_bounds__(256) void gates_kernel(const float* __restrict__ C2,
                                                    const float* __restrict__ P2,
                                                    float* __restrict__ g0,
                                                    float* __restrict__ g1) {
    int t = blockIdx.x * 256 + threadIdx.x;
    if (t >= S_) return;
    float d0 = 0.f;
    for (int k = 0; k < 64; ++k) d0 += C2[(size_t)t * 64 + k] * P2[(size_t)t * 64 + k];
    g0[t] = 1.0f / (1.0f + expf(-d0));
    float gg = 0.f;
    if (t & 1) {
        float d1 = 0.f;
        for (int k = 0; k < 64; ++k) d1 += C2[(size_t)t * 64 + k] * P2[(size_t)(t - 1) * 64 + k];
        gg = 1.0f / (1.0f + expf(-d1));
    }
    g1[t] = gg;
}

// ---------------- gated kv_t -> kve_full [B*S][288] + packed odd kvo [B][1024][296] ------
__global__ __launch_bounds__(256) void kve_kernel(const float* __restrict__ kv_c,
                                                  const float* __restrict__ kpe,
                                                  const float* __restrict__ g0,
                                                  const float* __restrict__ g1,
                                                  bf16* __restrict__ kve_full,
                                                  bf16* __restrict__ kvo) {
    int r = blockIdx.x, tid = threadIdx.x;
    int b = r >> 11, t = r & (S_ - 1);
    float a = g0[t], bb = g1[t];
    float v = a * kv_c[(size_t)r * 256 + tid];
    if (t & 1) v += bb * kv_c[(size_t)(r - 1) * 256 + tid];
    bf16 vb = __float2bfloat16(v);
    kve_full[(size_t)r * 288 + tid] = vb;
    if (t & 1) kvo[((size_t)b * 1024 + (t >> 1)) * 296 + tid] = vb;
    if (tid < 32) {
        float u = a * kpe[(size_t)r * 32 + tid];
        if (t & 1) u += bb * kpe[(size_t)(r - 1) * 32 + tid];
        bf16 ub = __float2bfloat16(u);
        kve_full[(size_t)r * 288 + 256 + tid] = ub;
        if (t & 1) kvo[((size_t)b * 1024 + (t >> 1)) * 296 + 256 + tid] = ub;
    }
}

// ---------------- kvoT32[b][uch][c][chunk] = kvo[b][uch*32 + tau(kslot)][c] --------------
// tau(8q+j) = (j<4) ? 4q+j : 16 + 4q + (j-4): makes the score C-layout line up
// register-for-slot with the 16x16x32 PV B-fragment. ADDITIONALLY the four 16B chunks of
// each c-row are stored XOR-swizzled (chunk' = chunk ^ ((c>>1)&3)) so that the linear
// global_load_lds staging lands a bank-conflict-free layout; the attn PV read applies
// the same XOR. (kvts rows are 64B -> without this, a 16-lane b128 beat is an 8-way
// bank conflict: banks repeat every 2 rows.)
__global__ __launch_bounds__(256) void kvoT32_kernel(const bf16* __restrict__ kvo,
                                                     bf16* __restrict__ kvoT) {
    int uch = blockIdx.x, b = blockIdx.y;
    int c = threadIdx.x;
    const bf16* src = kvo + ((size_t)b * 1024 + uch * 32) * 296 + c;
    short v[32];
#pragma unroll
    for (int j = 0; j < 32; ++j) v[j] = *(const short*)&src[(size_t)j * 296];
    bf16* dst = kvoT + (((size_t)b * 32 + uch) * 256 + c) * 32;
    int swz = (c >> 1) & 3;
#pragma unroll
    for (int q = 0; q < 4; ++q) {
        short8 o;
#pragma unroll
        for (int jj = 0; jj < 8; ++jj)
            o[jj] = (jj < 4) ? v[4 * q + jj] : v[16 + 4 * q + (jj - 4)];
        *(short8*)(void*)&dst[(q ^ swz) * 8] = o;
    }
}

// ---------------- roped, scaled q_pe -> qe[...,256:288) ----------------
__global__ __launch_bounds__(256) void rope_qe_kernel(const bf16* __restrict__ q,
                                                      bf16* __restrict__ qe) {
    int idx = blockIdx.x * 256 + threadIdx.x;
    if (idx >= B_ * S_ * H_ * 16) return;
    int j = idx & 15;
    int s = (idx >> 8) & (S_ - 1);
    float freq = expf(-(float)(2 * j) * 0.28782313662425572f);
    float ang = (float)s * freq;
    float c = cosf(ang), sn = sinf(ang);
    size_t row = idx >> 4;
    float a0 = bf2f(q[row * QKD_ + NOPE_ + 2 * j]);
    float a1 = bf2f(q[row * QKD_ + NOPE_ + 2 * j + 1]);
    qe[row * 288 + 256 + 2 * j]     = __float2bfloat16((a0 * c - a1 * sn) * SCALE_);
    qe[row * 288 + 256 + 2 * j + 1] = __float2bfloat16((a0 * sn + a1 * c) * SCALE_);
}

// ---------------- self scores: sscore[b][s][h] ----------------
__global__ __launch_bounds__(256) void sscore_kernel(const bf16* __restrict__ qe,
                                                     const bf16* __restrict__ kve_full,
                                                     float* __restrict__ sscore) {
    int s = blockIdx.x, b = blockIdx.y;
    int tid = threadIdx.x;
    int h = tid >> 4, p = tid & 15;
    const bf16* qrow = qe + ((size_t)(b * S_ + s) * H_ + h) * 288;
    const bf16* krow = kve_full + (size_t)(b * S_ + s) * 288;
    float d = 0.f;
#pragma unroll
    for (int e = 0; e < 18; ++e) d += bf2f(qrow[p * 18 + e]) * bf2f(krow[p * 18 + e]);
    d += __shfl_xor(d, 1);
    d += __shfl_xor(d, 2);
    d += __shfl_xor(d, 4);
    d += __shfl_xor(d, 8);
    if (p == 0) sscore[((size_t)(b * S_ + s)) * H_ + h] = d;
}

// ---------------- flash attention: 32-key tiles, 2 s-rows PER WAVE (8 rows/block) --------
// LDS was the bottleneck (R3 accounting: ~173 KB LDS traffic per block-iter for 4 rows ->
// ~56us of pure LDS BW). Each LDS read (score av, PV a8) now feeds TWO MFMAs (rows
// sA = s0+w, sB = s0+4+w) -> per-row LDS read traffic halves; block count halves so
// staging traffic halves too. PV reads use the XOR chunk swizzle (conflict-free).
// Complementary pairing: b=0 blocks descend in size, b=1 ascend, so each CU's two
// resident blocks sum to ~constant work.
__global__ __launch_bounds__(256, 2) void attn6_kernel(const bf16* __restrict__ qe,
                                                       const bf16* __restrict__ kvo,
                                                       const bf16* __restrict__ kvoT,
                                                       const bf16* __restrict__ kve_full,
                                                       const float* __restrict__ sscore,
                                                       bf16* __restrict__ xout) {
    int b = blockIdx.y;
    int sblk = (b == 0) ? ((int)gridDim.x - 1 - (int)blockIdx.x) : (int)blockIdx.x;
    int s0 = sblk * 8;
    int tid = threadIdx.x;
    int lane = tid & 63, w = tid >> 6;
    int q4 = lane >> 4, c16 = lane & 15;
    int sA = s0 + w, sB = s0 + 4 + w;
    int NoddA = (sA + 1) >> 1, NoddB = (sB + 1) >> 1;
    int niter = (((s0 + 8) >> 1) + 31) >> 5;

    __shared__ bf16 kvos[2][32][296];   // 2 x 18944 B: score-side K rows
    __shared__ bf16 kvts[2][256][32];   // 2 x 16384 B: PV-side V tile (tau+XOR layout)
    __shared__ bf16 selfr[8][256];      // self-key kv rows (8 s-rows)

    const bf16* kvob = kvo + (size_t)b * 1024 * 296;
    const bf16* kvoTb = kvoT + (size_t)b * 32 * 8192;

    {
        int rr = tid >> 5, ch = tid & 31;
        *(short8*)(void*)&selfr[rr][ch * 8] =
            *(const short8*)(const void*)&kve_full[(size_t)(b * S_ + s0 + rr) * 288 + ch * 8];
    }

    short8 qfA[9], qfB[9];
    const bf16* qrowA = qe + ((size_t)(b * S_ + sA) * H_ + c16) * 288;
    const bf16* qrowB = qe + ((size_t)(b * S_ + sB) * H_ + c16) * 288;
#pragma unroll
    for (int kk = 0; kk < 9; ++kk) {
        qfA[kk] = *(const short8*)(const void*)&qrowA[kk * 32 + q4 * 8];
        qfB[kk] = *(const short8*)(const void*)&qrowB[kk * 32 + q4 * 8];
    }

    floatx4 accA[16], accB[16];
#pragma unroll
    for (int n = 0; n < 16; ++n) {
        accA[n] = (floatx4){0.f, 0.f, 0.f, 0.f};
        accB[n] = (floatx4){0.f, 0.f, 0.f, 0.f};
    }
    float mA = -1e30f, lA = 0.f, mB = -1e30f, lB = 0.f;
    int swz = (c16 >> 1) & 3;  // PV chunk XOR (matches kvoT32 writer)

    // async stage of tile t into buffer p: kvos = 1184 16B chunks, kvts = 1024 16B chunks
    auto stage = [&](int t, int p) {
        const bf16* sa = kvob + (size_t)t * 32 * 296;
        bf16* la = &kvos[p][0][0];
#pragma unroll
        for (int i = 0; i < 4; ++i)
            g2l16(&sa[(size_t)(tid + i * 256) * 8], &la[(size_t)(tid + i * 256) * 8]);
        if (tid < 160) g2l16(&sa[(size_t)(tid + 1024) * 8], &la[(size_t)(tid + 1024) * 8]);
        const bf16* sb = kvoTb + (size_t)t * 8192;
        bf16* lb = &kvts[p][0][0];
#pragma unroll
        for (int i = 0; i < 4; ++i)
            g2l16(&sb[(size_t)(tid + i * 256) * 8], &lb[(size_t)(tid + i * 256) * 8]);
    };

    stage(0, 0);
    __syncthreads();  // prologue drain

    for (int it = 0; it < niter; ++it) {
        int p = it & 1;
        if (it + 1 < niter) stage(it + 1, 1 - p);  // lands during this iter's compute

        int u0 = it * 32;
        // scores^T: tile0 = keys u0+4q4+r (kvos rows c16), tile1 = keys u0+16+4q4+r.
        // Each LDS read feeds 2 MFMAs (rows A and B).
        floatx4 cA0 = (floatx4){0.f, 0.f, 0.f, 0.f}, cA1 = (floatx4){0.f, 0.f, 0.f, 0.f};
        floatx4 cB0 = (floatx4){0.f, 0.f, 0.f, 0.f}, cB1 = (floatx4){0.f, 0.f, 0.f, 0.f};
        __builtin_amdgcn_s_setprio(1);
#pragma unroll
        for (int kk = 0; kk < 9; ++kk) {
            short8 av0 = *(const short8*)(const void*)&kvos[p][c16][kk * 32 + q4 * 8];
            short8 av1 = *(const short8*)(const void*)&kvos[p][16 + c16][kk * 32 + q4 * 8];
            cA0 = __builtin_amdgcn_mfma_f32_16x16x32_bf16(av0, qfA[kk], cA0, 0, 0, 0);
            cB0 = __builtin_amdgcn_mfma_f32_16x16x32_bf16(av0, qfB[kk], cB0, 0, 0, 0);
            cA1 = __builtin_amdgcn_mfma_f32_16x16x32_bf16(av1, qfA[kk], cA1, 0, 0, 0);
            cB1 = __builtin_amdgcn_mfma_f32_16x16x32_bf16(av1, qfB[kk], cB1, 0, 0, 0);
        }
        __builtin_amdgcn_s_setprio(0);
        int k0i = u0 + q4 * 4;
        int k1i = u0 + 16 + q4 * 4;
#pragma unroll
        for (int r = 0; r < 4; ++r) {
            if (k0i + r >= NoddA) cA0[r] = -1e30f;
            if (k1i + r >= NoddA) cA1[r] = -1e30f;
            if (k0i + r >= NoddB) cB0[r] = -1e30f;
            if (k1i + r >= NoddB) cB1[r] = -1e30f;
        }
        // ---- softmax row A ----
        float tmaxA = fmaxf(fmaxf(fmaxf(cA0[0], cA0[1]), fmaxf(cA0[2], cA0[3])),
                            fmaxf(fmaxf(cA1[0], cA1[1]), fmaxf(cA1[2], cA1[3])));
        tmaxA = fmaxf(tmaxA, __shfl_xor(tmaxA, 16));
        tmaxA = fmaxf(tmaxA, __shfl_xor(tmaxA, 32));
        float mnA = fmaxf(mA, tmaxA);
        bool chgA = mnA > mA;
        float alA = __expf(mA - mnA);
        float pA0 = __expf(cA0[0] - mnA), pA1 = __expf(cA0[1] - mnA);
        float pA2 = __expf(cA0[2] - mnA), pA3 = __expf(cA0[3] - mnA);
        float pA4 = __expf(cA1[0] - mnA), pA5 = __expf(cA1[1] - mnA);
        float pA6 = __expf(cA1[2] - mnA), pA7 = __expf(cA1[3] - mnA);
        float rsA = (pA0 + pA1 + pA2 + pA3) + (pA4 + pA5 + pA6 + pA7);
        rsA += __shfl_xor(rsA, 16);
        rsA += __shfl_xor(rsA, 32);
        lA = lA * alA + rsA;
        mA = mnA;
        if (__any(chgA)) {
#pragma unroll
            for (int n = 0; n < 16; ++n) {
                accA[n][0] *= alA; accA[n][1] *= alA; accA[n][2] *= alA; accA[n][3] *= alA;
            }
        }
        // ---- softmax row B ----
        float tmaxB = fmaxf(fmaxf(fmaxf(cB0[0], cB0[1]), fmaxf(cB0[2], cB0[3])),
                            fmaxf(fmaxf(cB1[0], cB1[1]), fmaxf(cB1[2], cB1[3])));
        tmaxB = fmaxf(tmaxB, __shfl_xor(tmaxB, 16));
        tmaxB = fmaxf(tmaxB, __shfl_xor(tmaxB, 32));
        float mnB = fmaxf(mB, tmaxB);
        bool chgB = mnB > mB;
        float alB = __expf(mB - mnB);
        float pB0 = __expf(cB0[0] - mnB), pB1 = __expf(cB0[1] - mnB);
        float pB2 = __expf(cB0[2] - mnB), pB3 = __expf(cB0[3] - mnB);
        float pB4 = __expf(cB1[0] - mnB), pB5 = __expf(cB1[1] - mnB);
        float pB6 = __expf(cB1[2] - mnB), pB7 = __expf(cB1[3] - mnB);
        float rsB = (pB0 + pB1 + pB2 + pB3) + (pB4 + pB5 + pB6 + pB7);
        rsB += __shfl_xor(rsB, 16);
        rsB += __shfl_xor(rsB, 32);
        lB = lB * alB + rsB;
        mB = mnB;
        if (__any(chgB)) {
#pragma unroll
            for (int n = 0; n < 16; ++n) {
                accB[n][0] *= alB; accB[n][1] *= alB; accB[n][2] *= alB; accB[n][3] *= alB;
            }
        }
        // ---- PV: one a8 read feeds both rows' MFMAs ----
        short8 pfA, pfB;
        pfA[0] = f2bf_s(pA0); pfA[1] = f2bf_s(pA1); pfA[2] = f2bf_s(pA2); pfA[3] = f2bf_s(pA3);
        pfA[4] = f2bf_s(pA4); pfA[5] = f2bf_s(pA5); pfA[6] = f2bf_s(pA6); pfA[7] = f2bf_s(pA7);
        pfB[0] = f2bf_s(pB0); pfB[1] = f2bf_s(pB1); pfB[2] = f2bf_s(pB2); pfB[3] = f2bf_s(pB3);
        pfB[4] = f2bf_s(pB4); pfB[5] = f2bf_s(pB5); pfB[6] = f2bf_s(pB6); pfB[7] = f2bf_s(pB7);
        __builtin_amdgcn_s_setprio(1);
#pragma unroll
        for (int n = 0; n < 16; ++n) {
            short8 a8 = *(const short8*)(const void*)&kvts[p][n * 16 + c16][(q4 ^ swz) * 8];
            accA[n] = __builtin_amdgcn_mfma_f32_16x16x32_bf16(a8, pfA, accA[n], 0, 0, 0);
            accB[n] = __builtin_amdgcn_mfma_f32_16x16x32_bf16(a8, pfB, accB[n], 0, 0, 0);
        }
        __builtin_amdgcn_s_setprio(0);
        __syncthreads();  // done reading buf p; drains vmcnt -> next tile visible
    }

    // self key (even s only; odd s already in the odd set). sA,sB share parity of w.
    if ((w & 1) == 0) {
        float scsA = sscore[((size_t)(b * S_ + sA)) * H_ + c16];
        float mnA = fmaxf(mA, scsA);
        float alA = __expf(mA - mnA);
        float ppA = __expf(scsA - mnA);
        lA = lA * alA + ppA;
        float scsB = sscore[((size_t)(b * S_ + sB)) * H_ + c16];
        float mnB = fmaxf(mB, scsB);
        float alB = __expf(mB - mnB);
        float ppB = __expf(scsB - mnB);
        lB = lB * alB + ppB;
#pragma unroll
        for (int n = 0; n < 16; ++n) {
            short4v kvA = *(const short4v*)(const void*)&selfr[w][n * 16 + q4 * 4];
            short4v kvB = *(const short4v*)(const void*)&selfr[w + 4][n * 16 + q4 * 4];
#pragma unroll
            for (int r = 0; r < 4; ++r) {
                accA[n][r] = accA[n][r] * alA + ppA * s2f(kvA[r]);
                accB[n][r] = accB[n][r] * alB + ppB * s2f(kvB[r]);
            }
        }
    }

    float invlA = 1.0f / lA;
    float invlB = 1.0f / lB;
    bf16* orowA = xout + ((size_t)(b * S_ + sA) * H_ + c16) * 256;
    bf16* orowB = xout + ((size_t)(b * S_ + sB) * H_ + c16) * 256;
#pragma unroll
    for (int n = 0; n < 16; ++n) {
        short4v oA, oB;
#pragma unroll
        for (int r = 0; r < 4; ++r) {
            oA[r] = f2bf_s(accA[n][r] * invlA);
            oB[r] = f2bf_s(accB[n][r] * invlB);
        }
        *(short4v*)(void*)&orowA[n * 16 + q4 * 4] = oA;
        *(short4v*)(void*)&orowB[n * 16 + q4 * 4] = oB;
    }
}

extern "C" void kernel_launch(void* const* d_in, const int* in_sizes, int n_in,
                              void* d_out, int out_size, void* d_ws, size_t ws_size,
                              hipStream_t stream) {
    const float* hs     = (const float*)d_in[0];
    const float* wq     = (const float*)d_in[1];
    const float* wkv_a  = (const float*)d_in[2];
    const float* ln_g   = (const float*)d_in[3];
    const float* ln_b   = (const float*)d_in[4];
    const float* wkv_b  = (const float*)d_in[5];
    const float* wo     = (const float*)d_in[6];
    const float* fc_c_w = (const float*)d_in[7];
    const float* fc_c_b = (const float*)d_in[8];
    const float* fc_p_w = (const float*)d_in[9];
    const float* fc_p_b = (const float*)d_in[10];
    float* out = (float*)d_out;
    (void)in_sizes; (void)n_in; (void)out_size; (void)ws_size;

    const int M = B_ * S_;  // 4096
    char* wsb = (char*)d_ws;
    size_t o = 0;
    auto alloc = [&](size_t bytes) { char* p = wsb + o; o += (bytes + 255) & ~(size_t)255; return p; };

    bf16* qe = (bf16*)alloc((size_t)M * H_ * 288 * 2);  // 37.75 MB
    char* region2 = alloc((size_t)M * H_ * 256 * 2);    // 33.55 MB
    bf16* hs_bf    = (bf16*)region2;
    bf16* wq_bf    = (bf16*)(region2 + (size_t)M * E_ * 2);
    bf16* wkva_pad = (bf16*)(region2 + (size_t)M * E_ * 2 + (size_t)1536 * E_ * 2);
    bf16* x_bf     = (bf16*)region2;
    char* region3 = alloc((size_t)M * 1536 * 2);        // 12.58 MB
    bf16* q_bf    = (bf16*)region3;
    bf16* outp_bf = (bf16*)region3;
    float* kvraw = (float*)alloc((size_t)M * 384 * 4);
    float* kv_c  = (float*)alloc((size_t)M * 256 * 4);
    float* kpe   = (float*)alloc((size_t)M * 32 * 4);
    bf16* wo_bf   = (bf16*)alloc((size_t)E_ * 1024 * 2);
    bf16* wkvb_bf = (bf16*)alloc((size_t)2048 * 256 * 2);
    bf16* wkvbT   = (bf16*)alloc((size_t)H_ * 256 * 64 * 2);
    bf16* kve_full = (bf16*)alloc((size_t)M * 288 * 2);
    bf16* kvo      = (bf16*)alloc((size_t)B_ * 1024 * 296 * 2);
    bf16* kvoT     = (bf16*)alloc((size_t)B_ * 32 * 8192 * 2);
    float* sscore  = (float*)alloc((size_t)M * H_ * 4);
    float* C2 = (float*)alloc((size_t)S_ * 64 * 4);
    float* P2 = (float*)alloc((size_t)S_ * 64 * 4);
    float* g0 = (float*)alloc(S_ * 4);
    float* g1 = (float*)alloc(S_ * 4);

    // fused conversions (hs, wq, wo, wkv_b, wkva_pad) — one launch
    conv_fused_kernel<<<(CV_N4 + 255) / 256, 256, 0, stream>>>(
        hs, wq, wo, wkv_b, wkv_a, hs_bf, wq_bf, wo_bf, wkvb_bf, wkva_pad);
    transpose_wkvbT_kernel<<<H_, 256, 0, stream>>>(wkv_b, wkvbT);
    // fused projections: q (bf16) + kvraw (f32) in ONE launch (480 blocks)
    gemm_qkv_fused<<<dim3(15, M / 128), 256, 0, stream>>>(hs_bf, wq_bf, wkva_pad, q_bf, kvraw, E_);
    // LN + k_pe rope
    ln_rope_kernel<<<M, 256, 0, stream>>>(kvraw, ln_g, ln_b, kv_c, kpe);
    // gates
    c2p2_kernel<<<S_, 64, 0, stream>>>(fc_c_w, fc_c_b, fc_p_w, fc_p_b, C2, P2);
    gates_kernel<<<(S_ + 255) / 256, 256, 0, stream>>>(C2, P2, g0, g1);
    // kve (full + packed odd) and 32-key tau+XOR-permuted transpose
    kve_kernel<<<M, 256, 0, stream>>>(kv_c, kpe, g0, g1, kve_full, kvo);
    kvoT32_kernel<<<dim3(32, B_), 256, 0, stream>>>(kvo, kvoT);
    // qe = [q_abs * SCALE | rope(q_pe) * SCALE]
    gemm64_lds<bf16><<<dim3(256 / 64, M / 64, H_), 256, 0, stream>>>(
        q_bf, H_ * QKD_, QKD_, wkvbT, 64, 256 * 64, qe, H_ * 288, 288, 64, SCALE_);
    rope_qe_kernel<<<(M * H_ * 16 + 255) / 256, 256, 0, stream>>>(q_bf, qe);
    // self scores
    sscore_kernel<<<dim3(S_, B_), 256, 0, stream>>>(qe, kve_full, sscore);
    // attention (32-key tiles, 2 s-rows per wave, 8 rows/block)
    attn6_kernel<<<dim3(S_ / 8, B_), 256, 0, stream>>>(qe, kvo, kvoT, kve_full, sscore, x_bf);
    // V-projection per head
    gemm64_lds<bf16><<<dim3(1, M / 64, H_), 256, 0, stream>>>(
        x_bf, H_ * 256, 256, wkvb_bf + (size_t)64 * 256, 256, 128 * 256, outp_bf, 1024, 64, 256, 1.0f);
    // final out = outp @ wo^T
    gemm_bt_lds<float><<<dim3(E_ / 128, M / 128), 256, 0, stream>>>(outp_bf, wo_bf, out, M, E_, 1024);
}

// Round 5
// 355.143 us; speedup vs baseline: 1.0508x; 1.0508x over previous
//
#include <hip/hip_runtime.h>
#include <hip/hip_bf16.h>
#include <math.h>
#include <stdint.h>

#define B_ 2
#define S_ 2048
#define E_ 2048
#define H_ 16
#define NOPE_ 64
#define ROPE_ 32
#define V_ 64
#define KVR_ 256
#define QKD_ 96
#define SCALE_ 0.10206207261596577f  /* 96^-0.5 */

typedef __hip_bfloat16 bf16;
typedef __attribute__((ext_vector_type(8))) short short8;
typedef __attribute__((ext_vector_type(4))) short short4v;
typedef __attribute__((ext_vector_type(4))) float floatx4;

__device__ __forceinline__ float bf2f(bf16 v) { return __bfloat162float(v); }
__device__ __forceinline__ float s2f(short v) {
    bf16 h = *reinterpret_cast<bf16*>(&v);
    return __bfloat162float(h);
}
__device__ __forceinline__ short f2bf_s(float f) {
    bf16 h = __float2bfloat16(f);
    return *reinterpret_cast<short*>(&h);
}
__device__ __forceinline__ void store_c(float* C, size_t i, float v) { C[i] = v; }
__device__ __forceinline__ void store_c(bf16* C, size_t i, float v) { C[i] = __float2bfloat16(v); }

// async 16B global -> LDS. Proper addrspacecasts (NO integer truncation — flat LDS
// addresses are aperture-based; C-style cast emits the correct addrspacecast).
__device__ __forceinline__ void g2l16(const bf16* g, bf16* l) {
    __builtin_amdgcn_global_load_lds(
        (const __attribute__((address_space(1))) void*)g,
        (__attribute__((address_space(3))) void*)l,
        16, 0, 0);
}

// ---------------- fused fp32 -> bf16 conversions (hs, wq, wo, wkv_b, wkv_a-pad) ----------
#define CV_N0 1048576              /* hs:    4096*2048/8 */
#define CV_N1 (CV_N0 + 393216)     /* wq:    1536*2048/8 */
#define CV_N2 (CV_N1 + 262144)     /* wo:    2048*1024/8 */
#define CV_N3 (CV_N2 + 65536)      /* wkv_b: 2048*256/8  */
#define CV_N4 (CV_N3 + 98304)      /* wkva_pad: 384*2048/8 */
__global__ __launch_bounds__(256) void conv_fused_kernel(const float* __restrict__ hs,
                                                         const float* __restrict__ wq,
                                                         const float* __restrict__ wo,
                                                         const float* __restrict__ wkv_b,
                                                         const float* __restrict__ wkv_a,
                                                         bf16* __restrict__ hs_bf,
                                                         bf16* __restrict__ wq_bf,
                                                         bf16* __restrict__ wo_bf,
                                                         bf16* __restrict__ wkvb_bf,
                                                         bf16* __restrict__ wkva_pad) {
    int i = blockIdx.x * 256 + threadIdx.x;
    const float* src;
    bf16* dst;
    int j;
    if (i < CV_N0)      { src = hs;    dst = hs_bf;   j = i; }
    else if (i < CV_N1) { src = wq;    dst = wq_bf;   j = i - CV_N0; }
    else if (i < CV_N2) { src = wo;    dst = wo_bf;   j = i - CV_N1; }
    else if (i < CV_N3) { src = wkv_b; dst = wkvb_bf; j = i - CV_N2; }
    else if (i < CV_N4) {
        j = i - CV_N3;
        int row = j >> 8;
        short8 r;
        if (row < 288) {
            float4 a = ((const float4*)wkv_a)[2 * j];
            float4 b = ((const float4*)wkv_a)[2 * j + 1];
            r[0] = f2bf_s(a.x); r[1] = f2bf_s(a.y); r[2] = f2bf_s(a.z); r[3] = f2bf_s(a.w);
            r[4] = f2bf_s(b.x); r[5] = f2bf_s(b.y); r[6] = f2bf_s(b.z); r[7] = f2bf_s(b.w);
        } else {
            for (int k = 0; k < 8; ++k) r[k] = 0;
        }
        ((short8*)wkva_pad)[j] = r;
        return;
    } else return;
    float4 a = ((const float4*)src)[2 * j];
    float4 b = ((const float4*)src)[2 * j + 1];
    short8 r;
    r[0] = f2bf_s(a.x); r[1] = f2bf_s(a.y); r[2] = f2bf_s(a.z); r[3] = f2bf_s(a.w);
    r[4] = f2bf_s(b.x); r[5] = f2bf_s(b.y); r[6] = f2bf_s(b.z); r[7] = f2bf_s(b.w);
    ((short8*)dst)[j] = r;
}

// ---------------- wkvbT[h][c][d] = bf16(wkv_b[h*128+d][c]), d<64 ----------------
__global__ __launch_bounds__(256) void transpose_wkvbT_kernel(const float* __restrict__ wkv_b,
                                                              bf16* __restrict__ wkvbT) {
    int h = blockIdx.x, c = threadIdx.x;
#pragma unroll
    for (int d0 = 0; d0 < 64; d0 += 8) {
        short8 v;
#pragma unroll
        for (int j = 0; j < 8; ++j) v[j] = f2bf_s(wkv_b[(size_t)(h * 128 + d0 + j) * 256 + c]);
        *(short8*)(void*)&wkvbT[((size_t)h * 256 + c) * 64 + d0] = v;
    }
}

// ---------------- bf16 MFMA GEMM (m97-style): C(M,N) = A(M,K) @ B(N,K)^T ----------------
template <typename TC>
__global__ __launch_bounds__(256, 2) void gemm_bt_lds(const bf16* __restrict__ A,
                                                      const bf16* __restrict__ Bm,
                                                      TC* __restrict__ C,
                                                      int M, int N, int K) {
    __shared__ bf16 Asf[128 * 32];
    __shared__ bf16 Bsf[128 * 32];
    int tid = threadIdx.x;
    int lane = tid & 63, w = tid >> 6;
    int q4 = lane >> 4, c16 = lane & 15;
    int wr = w >> 1, wc = w & 1;
    int m0 = blockIdx.y * 128, n0 = blockIdx.x * 128;
    floatx4 acc[4][4];
#pragma unroll
    for (int mi = 0; mi < 4; ++mi)
#pragma unroll
        for (int ni = 0; ni < 4; ++ni) acc[mi][ni] = (floatx4){0.f, 0.f, 0.f, 0.f};

    for (int k0 = 0; k0 < K; k0 += 32) {
        __syncthreads();
#pragma unroll
        for (int i = 0; i < 2; ++i) {
            int c = (w << 6) + lane + i * 256;
            int row = c >> 2, kc = c & 3;
            g2l16(&A[(size_t)(m0 + row) * K + k0 + kc * 8], &Asf[c * 8]);
            g2l16(&Bm[(size_t)(n0 + row) * K + k0 + kc * 8], &Bsf[c * 8]);
        }
        __syncthreads();
        short8 af[4], bfr[4];
#pragma unroll
        for (int mi = 0; mi < 4; ++mi)
            af[mi] = *(const short8*)(const void*)&Asf[(wr * 64 + mi * 16 + c16) * 32 + q4 * 8];
#pragma unroll
        for (int ni = 0; ni < 4; ++ni)
            bfr[ni] = *(const short8*)(const void*)&Bsf[(wc * 64 + ni * 16 + c16) * 32 + q4 * 8];
#pragma unroll
        for (int mi = 0; mi < 4; ++mi)
#pragma unroll
            for (int ni = 0; ni < 4; ++ni)
                acc[mi][ni] = __builtin_amdgcn_mfma_f32_16x16x32_bf16(af[mi], bfr[ni], acc[mi][ni], 0, 0, 0);
    }
#pragma unroll
    for (int mi = 0; mi < 4; ++mi)
#pragma unroll
        for (int ni = 0; ni < 4; ++ni)
#pragma unroll
            for (int r = 0; r < 4; ++r) {
                int row = m0 + wr * 64 + mi * 16 + q4 * 4 + r;
                int col = n0 + wc * 64 + ni * 16 + c16;
                store_c(C, (size_t)row * N + col, acc[mi][ni][r]);
            }
}

// ---------------- fused projection GEMM: q (bf16 out, N=1536) + kvraw (f32 out, N=384) ---
__global__ __launch_bounds__(256, 2) void gemm_qkv_fused(const bf16* __restrict__ A,
                                                         const bf16* __restrict__ Bq,
                                                         const bf16* __restrict__ Bkv,
                                                         bf16* __restrict__ Cq,
                                                         float* __restrict__ Ckv,
                                                         int K) {
    __shared__ bf16 Asf[128 * 32];
    __shared__ bf16 Bsf[128 * 32];
    int tid = threadIdx.x;
    int lane = tid & 63, w = tid >> 6;
    int q4 = lane >> 4, c16 = lane & 15;
    int wr = w >> 1, wc = w & 1;
    int bx = blockIdx.x;
    bool isq = bx < 12;
    const bf16* Bm = isq ? Bq : Bkv;
    int n0 = isq ? bx * 128 : (bx - 12) * 128;
    int m0 = blockIdx.y * 128;
    floatx4 acc[4][4];
#pragma unroll
    for (int mi = 0; mi < 4; ++mi)
#pragma unroll
        for (int ni = 0; ni < 4; ++ni) acc[mi][ni] = (floatx4){0.f, 0.f, 0.f, 0.f};

    for (int k0 = 0; k0 < K; k0 += 32) {
        __syncthreads();
#pragma unroll
        for (int i = 0; i < 2; ++i) {
            int c = (w << 6) + lane + i * 256;
            int row = c >> 2, kc = c & 3;
            g2l16(&A[(size_t)(m0 + row) * K + k0 + kc * 8], &Asf[c * 8]);
            g2l16(&Bm[(size_t)(n0 + row) * K + k0 + kc * 8], &Bsf[c * 8]);
        }
        __syncthreads();
        short8 af[4], bfr[4];
#pragma unroll
        for (int mi = 0; mi < 4; ++mi)
            af[mi] = *(const short8*)(const void*)&Asf[(wr * 64 + mi * 16 + c16) * 32 + q4 * 8];
#pragma unroll
        for (int ni = 0; ni < 4; ++ni)
            bfr[ni] = *(const short8*)(const void*)&Bsf[(wc * 64 + ni * 16 + c16) * 32 + q4 * 8];
#pragma unroll
        for (int mi = 0; mi < 4; ++mi)
#pragma unroll
            for (int ni = 0; ni < 4; ++ni)
                acc[mi][ni] = __builtin_amdgcn_mfma_f32_16x16x32_bf16(af[mi], bfr[ni], acc[mi][ni], 0, 0, 0);
    }
#pragma unroll
    for (int mi = 0; mi < 4; ++mi)
#pragma unroll
        for (int ni = 0; ni < 4; ++ni)
#pragma unroll
            for (int r = 0; r < 4; ++r) {
                int row = m0 + wr * 64 + mi * 16 + q4 * 4 + r;
                int col = n0 + wc * 64 + ni * 16 + c16;
                if (isq)
                    Cq[(size_t)row * 1536 + col] = __float2bfloat16(acc[mi][ni][r]);
                else
                    Ckv[(size_t)row * 384 + col] = acc[mi][ni][r];
            }
}

// ---------------- small batched bf16 MFMA GEMM (64x64 tiles, global_load_lds) -------------
template <typename TC>
__global__ __launch_bounds__(256, 4) void gemm64_lds(const bf16* __restrict__ A, int lda, int aoffz,
                                                     const bf16* __restrict__ Bm, int ldb, int boffz,
                                                     TC* __restrict__ C, int ldc, int coffz,
                                                     int K, float scale) {
    int z = blockIdx.z;
    A += (size_t)z * aoffz;
    Bm += (size_t)z * boffz;
    C += (size_t)z * coffz;
    __shared__ bf16 Asf[64 * 32];
    __shared__ bf16 Bsf[64 * 32];
    int tid = threadIdx.x;
    int lane = tid & 63, w = tid >> 6;
    int q4 = lane >> 4, c16 = lane & 15;
    int m0 = blockIdx.y * 64, n0 = blockIdx.x * 64;
    floatx4 acc[4];
#pragma unroll
    for (int ni = 0; ni < 4; ++ni) acc[ni] = (floatx4){0.f, 0.f, 0.f, 0.f};
    int row = tid >> 2, kc = tid & 3;
    for (int k0 = 0; k0 < K; k0 += 32) {
        __syncthreads();
        g2l16(&A[(size_t)(m0 + row) * lda + k0 + kc * 8], &Asf[tid * 8]);
        g2l16(&Bm[(size_t)(n0 + row) * ldb + k0 + kc * 8], &Bsf[tid * 8]);
        __syncthreads();
        short8 af = *(const short8*)(const void*)&Asf[(w * 16 + c16) * 32 + q4 * 8];
#pragma unroll
        for (int ni = 0; ni < 4; ++ni) {
            short8 bfr = *(const short8*)(const void*)&Bsf[(ni * 16 + c16) * 32 + q4 * 8];
            acc[ni] = __builtin_amdgcn_mfma_f32_16x16x32_bf16(af, bfr, acc[ni], 0, 0, 0);
        }
    }
#pragma unroll
    for (int ni = 0; ni < 4; ++ni)
#pragma unroll
        for (int rr = 0; rr < 4; ++rr)
            store_c(C, (size_t)(m0 + w * 16 + q4 * 4 + rr) * ldc + n0 + ni * 16 + c16,
                    acc[ni][rr] * scale);
}

// ---------------- LayerNorm(kv_c) + RoPE(k_pe); input stride 384 ----------------
__global__ __launch_bounds__(256) void ln_rope_kernel(const float* __restrict__ kvraw,
                                                      const float* __restrict__ g,
                                                      const float* __restrict__ bta,
                                                      float* __restrict__ kv_c,
                                                      float* __restrict__ kpe) {
    int r = blockIdx.x;
    int tid = threadIdx.x;
    int lane = tid & 63, w = tid >> 6;
    float x = kvraw[(size_t)r * 384 + tid];
    float v1 = x, v2 = x * x;
#pragma unroll
    for (int o = 32; o; o >>= 1) { v1 += __shfl_down(v1, o); v2 += __shfl_down(v2, o); }
    __shared__ float s1[4], s2[4], stats[2];
    if (lane == 0) { s1[w] = v1; s2[w] = v2; }
    __syncthreads();
    if (tid == 0) {
        float S1 = s1[0] + s1[1] + s1[2] + s1[3];
        float S2 = s2[0] + s2[1] + s2[2] + s2[3];
        float mean = S1 / 256.0f;
        float var = S2 / 256.0f - mean * mean;
        stats[0] = mean;
        stats[1] = rsqrtf(var + 1e-5f);
    }
    __syncthreads();
    float y = (x - stats[0]) * stats[1] * g[tid] + bta[tid];
    kv_c[(size_t)r * 256 + tid] = y;
    if (tid < 16) {
        int j = tid;
        int s = r & (S_ - 1);
        float freq = expf(-(float)(2 * j) * 0.28782313662425572f);  // ln(1e4)/32
        float ang = (float)s * freq;
        float c = cosf(ang), sn = sinf(ang);
        float x0 = kvraw[(size_t)r * 384 + 256 + 2 * j];
        float x1 = kvraw[(size_t)r * 384 + 256 + 2 * j + 1];
        kpe[(size_t)r * 32 + 2 * j]     = x0 * c - x1 * sn;
        kpe[(size_t)r * 32 + 2 * j + 1] = x0 * sn + x1 * c;
    }
}

// ---------------- C2 / P2 ----------------
__global__ __launch_bounds__(64) void c2p2_kernel(const float* __restrict__ fcw_c,
                                                  const float* __restrict__ fcb_c,
                                                  const float* __restrict__ fcw_p,
                                                  const float* __restrict__ fcb_p,
                                                  float* __restrict__ C2,
                                                  float* __restrict__ P2) {
    int t = blockIdx.x;
    int k = threadIdx.x;
    __shared__ float Crow[256], Prow[256];
    for (int i = k; i < 128; i += 64) {
        float div = expf(-(float)i * 0.07195578415606393f);  // ln(1e4)/128
        float ap = (float)t * div;
        Prow[2 * i]     = sinf(ap);
        Prow[2 * i + 1] = cosf(ap);
        float ac = (float)(t >> 1) * div;
        Crow[2 * i]     = sinf(ac);
        Crow[2 * i + 1] = cosf(ac);
    }
    __syncthreads();
    float sc = fcb_c[k], sp = fcb_p[k];
    for (int c = 0; c < 256; ++c) {
        sc += Crow[c] * fcw_c[(size_t)k * 256 + c];
        sp += Prow[c] * fcw_p[(size_t)k * 256 + c];
    }
    C2[(size_t)t * 64 + k] = sc;
    P2[(size_t)t * 64 + k] = sp;
}

__global__ __launch_bounds__(256) void gates_kernel(const float* __restrict__ C2,
                                                    const float* __restrict__ P2,
                                                    float* __restrict__ g0,
                                                    float* __restrict__ g1) {
    int t = blockIdx.x * 256 + threadIdx.x;
    if (t >= S_) return;
    float d0 = 0.f;
    for (int k = 0; k < 64; ++k) d0 += C2[(size_t)t * 64 + k] * P2[(size_t)t * 64 + k];
    g0[t] = 1.0f / (1.0f + expf(-d0));
    float gg = 0.f;
    if (t & 1) {
        float d1 = 0.f;
        for (int k = 0; k < 64; ++k) d1 += C2[(size_t)t * 64 + k] * P2[(size_t)(t - 1) * 64 + k];
        gg = 1.0f / (1.0f + expf(-d1));
    }
    g1[t] = gg;
}

// ---------------- gated kv_t -> kve_full [B*S][288] + packed odd kvo [B][1024][296] ------
__global__ __launch_bounds__(256) void kve_kernel(const float* __restrict__ kv_c,
                                                  const float* __restrict__ kpe,
                                                  const float* __restrict__ g0,
                                                  const float* __restrict__ g1,
                                                  bf16* __restrict__ kve_full,
                                                  bf16* __restrict__ kvo) {
    int r = blockIdx.x, tid = threadIdx.x;
    int b = r >> 11, t = r & (S_ - 1);
    float a = g0[t], bb = g1[t];
    float v = a * kv_c[(size_t)r * 256 + tid];
    if (t & 1) v += bb * kv_c[(size_t)(r - 1) * 256 + tid];
    bf16 vb = __float2bfloat16(v);
    kve_full[(size_t)r * 288 + tid] = vb;
    if (t & 1) kvo[((size_t)b * 1024 + (t >> 1)) * 296 + tid] = vb;
    if (tid < 32) {
        float u = a * kpe[(size_t)r * 32 + tid];
        if (t & 1) u += bb * kpe[(size_t)(r - 1) * 32 + tid];
        bf16 ub = __float2bfloat16(u);
        kve_full[(size_t)r * 288 + 256 + tid] = ub;
        if (t & 1) kvo[((size_t)b * 1024 + (t >> 1)) * 296 + 256 + tid] = ub;
    }
}

// ---------------- kvoT32[b][uch][c][chunk] = kvo[b][uch*32 + tau(kslot)][c] --------------
// tau(8q+j) = (j<4) ? 4q+j : 16 + 4q + (j-4): makes the score C-layout line up
// register-for-slot with the 16x16x32 PV B-fragment. ADDITIONALLY the four 16B chunks of
// each c-row are stored XOR-swizzled (chunk' = chunk ^ ((c>>1)&3)) so that the linear
// global_load_lds staging lands a bank-conflict-free layout; the attn PV read applies
// the same XOR. (kvts rows are 64B -> without this, a 16-lane b128 beat is an 8-way
// bank conflict. HW-verified in R4: conflicts 9.19M -> 2.43M.)
__global__ __launch_bounds__(256) void kvoT32_kernel(const bf16* __restrict__ kvo,
                                                     bf16* __restrict__ kvoT) {
    int uch = blockIdx.x, b = blockIdx.y;
    int c = threadIdx.x;
    const bf16* src = kvo + ((size_t)b * 1024 + uch * 32) * 296 + c;
    short v[32];
#pragma unroll
    for (int j = 0; j < 32; ++j) v[j] = *(const short*)&src[(size_t)j * 296];
    bf16* dst = kvoT + (((size_t)b * 32 + uch) * 256 + c) * 32;
    int swz = (c >> 1) & 3;
#pragma unroll
    for (int q = 0; q < 4; ++q) {
        short8 o;
#pragma unroll
        for (int jj = 0; jj < 8; ++jj)
            o[jj] = (jj < 4) ? v[4 * q + jj] : v[16 + 4 * q + (jj - 4)];
        *(short8*)(void*)&dst[(q ^ swz) * 8] = o;
    }
}

// ---------------- roped, scaled q_pe -> qe[...,256:288) ----------------
__global__ __launch_bounds__(256) void rope_qe_kernel(const bf16* __restrict__ q,
                                                      bf16* __restrict__ qe) {
    int idx = blockIdx.x * 256 + threadIdx.x;
    if (idx >= B_ * S_ * H_ * 16) return;
    int j = idx & 15;
    int s = (idx >> 8) & (S_ - 1);
    float freq = expf(-(float)(2 * j) * 0.28782313662425572f);
    float ang = (float)s * freq;
    float c = cosf(ang), sn = sinf(ang);
    size_t row = idx >> 4;
    float a0 = bf2f(q[row * QKD_ + NOPE_ + 2 * j]);
    float a1 = bf2f(q[row * QKD_ + NOPE_ + 2 * j + 1]);
    qe[row * 288 + 256 + 2 * j]     = __float2bfloat16((a0 * c - a1 * sn) * SCALE_);
    qe[row * 288 + 256 + 2 * j + 1] = __float2bfloat16((a0 * sn + a1 * c) * SCALE_);
}

// ---------------- self scores: sscore[b][s][h] ----------------
__global__ __launch_bounds__(256) void sscore_kernel(const bf16* __restrict__ qe,
                                                     const bf16* __restrict__ kve_full,
                                                     float* __restrict__ sscore) {
    int s = blockIdx.x, b = blockIdx.y;
    int tid = threadIdx.x;
    int h = tid >> 4, p = tid & 15;
    const bf16* qrow = qe + ((size_t)(b * S_ + s) * H_ + h) * 288;
    const bf16* krow = kve_full + (size_t)(b * S_ + s) * 288;
    float d = 0.f;
#pragma unroll
    for (int e = 0; e < 18; ++e) d += bf2f(qrow[p * 18 + e]) * bf2f(krow[p * 18 + e]);
    d += __shfl_xor(d, 1);
    d += __shfl_xor(d, 2);
    d += __shfl_xor(d, 4);
    d += __shfl_xor(d, 8);
    if (p == 0) sscore[((size_t)(b * S_ + s)) * H_ + h] = d;
}

// ---------------- flash attention: 32-key tiles, double-buffered, XOR-swizzled PV --------
// attn5 structure (R3: 78.6us, best measured) + the HW-verified PV chunk swizzle from R4
// (conflicts 9.19M -> 2.43M, ~11us of LDS conflict cycles). 4 rows/block, 1024 blocks.
__global__ __launch_bounds__(256, 2) void attn7_kernel(const bf16* __restrict__ qe,
                                                       const bf16* __restrict__ kvo,
                                                       const bf16* __restrict__ kvoT,
                                                       const bf16* __restrict__ kve_full,
                                                       const float* __restrict__ sscore,
                                                       bf16* __restrict__ xout) {
    int s0 = (int)(gridDim.x - 1 - blockIdx.x) * 4;  // biggest blocks first
    int b = blockIdx.y;
    int tid = threadIdx.x;
    int lane = tid & 63, w = tid >> 6;
    int q4 = lane >> 4, c16 = lane & 15;
    int s = s0 + w;
    int Nodd = (s + 1) >> 1;
    int NoddMax = (s0 + 4) >> 1;
    int niter = (NoddMax + 31) >> 5;

    __shared__ bf16 kvos[2][32][296];   // 2 x 18944 B: score-side K rows
    __shared__ bf16 kvts[2][256][32];   // 2 x 16384 B: PV-side V tile (tau+XOR layout)
    __shared__ bf16 selfr[4][256];      // self-key kv rows

    const bf16* kvob = kvo + (size_t)b * 1024 * 296;
    const bf16* kvoTb = kvoT + (size_t)b * 32 * 8192;

    if (tid < 128) {
        int rr = tid >> 5, ch = tid & 31;
        *(short8*)(void*)&selfr[rr][ch * 8] =
            *(const short8*)(const void*)&kve_full[(size_t)(b * S_ + s0 + rr) * 288 + ch * 8];
    }

    short8 qf[9];
    const bf16* qrow = qe + ((size_t)(b * S_ + s) * H_ + c16) * 288;
#pragma unroll
    for (int kk = 0; kk < 9; ++kk) qf[kk] = *(const short8*)(const void*)&qrow[kk * 32 + q4 * 8];

    floatx4 acc[16];
#pragma unroll
    for (int n = 0; n < 16; ++n) acc[n] = (floatx4){0.f, 0.f, 0.f, 0.f};
    float m_i = -1e30f, l_i = 0.f;
    int swz = (c16 >> 1) & 3;  // PV chunk XOR (matches kvoT32 writer)

    // async stage of tile t into buffer p: kvos = 1184 16B chunks, kvts = 1024 16B chunks
    auto stage = [&](int t, int p) {
        const bf16* sa = kvob + (size_t)t * 32 * 296;
        bf16* la = &kvos[p][0][0];
#pragma unroll
        for (int i = 0; i < 4; ++i)
            g2l16(&sa[(size_t)(tid + i * 256) * 8], &la[(size_t)(tid + i * 256) * 8]);
        if (tid < 160) g2l16(&sa[(size_t)(tid + 1024) * 8], &la[(size_t)(tid + 1024) * 8]);
        const bf16* sb = kvoTb + (size_t)t * 8192;
        bf16* lb = &kvts[p][0][0];
#pragma unroll
        for (int i = 0; i < 4; ++i)
            g2l16(&sb[(size_t)(tid + i * 256) * 8], &lb[(size_t)(tid + i * 256) * 8]);
    };

    stage(0, 0);
    __syncthreads();  // prologue drain

    for (int it = 0; it < niter; ++it) {
        int p = it & 1;
        // Issue next tile's loads FIRST — they land during this iteration's compute.
        if (it + 1 < niter) stage(it + 1, 1 - p);

        int u0 = it * 32;
        // scores^T for 32 keys: tile A = rows c16 (keys u0+4q4+r), tile B = rows 16+c16.
        floatx4 ca0 = (floatx4){0.f, 0.f, 0.f, 0.f}, ca1 = (floatx4){0.f, 0.f, 0.f, 0.f};
        floatx4 cb0 = (floatx4){0.f, 0.f, 0.f, 0.f}, cb1 = (floatx4){0.f, 0.f, 0.f, 0.f};
        __builtin_amdgcn_s_setprio(1);
#pragma unroll
        for (int kk = 0; kk < 9; ++kk) {
            short8 avA = *(const short8*)(const void*)&kvos[p][c16][kk * 32 + q4 * 8];
            short8 avB = *(const short8*)(const void*)&kvos[p][16 + c16][kk * 32 + q4 * 8];
            if (kk & 1) {
                ca1 = __builtin_amdgcn_mfma_f32_16x16x32_bf16(avA, qf[kk], ca1, 0, 0, 0);
                cb1 = __builtin_amdgcn_mfma_f32_16x16x32_bf16(avB, qf[kk], cb1, 0, 0, 0);
            } else {
                ca0 = __builtin_amdgcn_mfma_f32_16x16x32_bf16(avA, qf[kk], ca0, 0, 0, 0);
                cb0 = __builtin_amdgcn_mfma_f32_16x16x32_bf16(avB, qf[kk], cb0, 0, 0, 0);
            }
        }
        __builtin_amdgcn_s_setprio(0);
        floatx4 cA = ca0 + ca1;
        floatx4 cB = cb0 + cb1;
        int kA = u0 + q4 * 4;
        int kB = u0 + 16 + q4 * 4;
#pragma unroll
        for (int r = 0; r < 4; ++r) {
            if (kA + r >= Nodd) cA[r] = -1e30f;
            if (kB + r >= Nodd) cB[r] = -1e30f;
        }
        float tmax = fmaxf(fmaxf(fmaxf(cA[0], cA[1]), fmaxf(cA[2], cA[3])),
                           fmaxf(fmaxf(cB[0], cB[1]), fmaxf(cB[2], cB[3])));
        tmax = fmaxf(tmax, __shfl_xor(tmax, 16));
        tmax = fmaxf(tmax, __shfl_xor(tmax, 32));
        float mn = fmaxf(m_i, tmax);
        bool chg = mn > m_i;
        float al = __expf(m_i - mn);
        float pA0 = __expf(cA[0] - mn), pA1 = __expf(cA[1] - mn);
        float pA2 = __expf(cA[2] - mn), pA3 = __expf(cA[3] - mn);
        float pB0 = __expf(cB[0] - mn), pB1 = __expf(cB[1] - mn);
        float pB2 = __expf(cB[2] - mn), pB3 = __expf(cB[3] - mn);
        float rs = (pA0 + pA1 + pA2 + pA3) + (pB0 + pB1 + pB2 + pB3);
        rs += __shfl_xor(rs, 16);
        rs += __shfl_xor(rs, 32);
        l_i = l_i * al + rs;
        m_i = mn;
        if (__any(chg)) {
#pragma unroll
            for (int n = 0; n < 16; ++n) {
                acc[n][0] *= al; acc[n][1] *= al; acc[n][2] *= al; acc[n][3] *= al;
            }
        }
        // PV with 16x16x32: B-frag k-slot q4*8+j maps to key tau(q4*8+j); kvts stores V
        // in the same tau order; chunk XOR de-conflicts the read.
        short8 pf;
        pf[0] = f2bf_s(pA0); pf[1] = f2bf_s(pA1); pf[2] = f2bf_s(pA2); pf[3] = f2bf_s(pA3);
        pf[4] = f2bf_s(pB0); pf[5] = f2bf_s(pB1); pf[6] = f2bf_s(pB2); pf[7] = f2bf_s(pB3);
        __builtin_amdgcn_s_setprio(1);
#pragma unroll
        for (int n = 0; n < 16; ++n) {
            short8 a8 = *(const short8*)(const void*)&kvts[p][n * 16 + c16][(q4 ^ swz) * 8];
            acc[n] = __builtin_amdgcn_mfma_f32_16x16x32_bf16(a8, pf, acc[n], 0, 0, 0);
        }
        __builtin_amdgcn_s_setprio(0);
        // ONE barrier per iteration: (a) all waves done reading buffer p;
        // (b) implicit vmcnt(0) drain makes tile it+1 (issued at iter start) visible.
        __syncthreads();
    }

    // self key (even s; odd s already included in odd set)
    if ((s & 1) == 0) {
        float scs = sscore[((size_t)(b * S_ + s)) * H_ + c16];
        float mn = fmaxf(m_i, scs);
        float al = __expf(m_i - mn);
        float pp = __expf(scs - mn);
        l_i = l_i * al + pp;
        m_i = mn;
#pragma unroll
        for (int n = 0; n < 16; ++n) {
            short4v kv4 = *(const short4v*)(const void*)&selfr[w][n * 16 + q4 * 4];
#pragma unroll
            for (int r = 0; r < 4; ++r)
                acc[n][r] = acc[n][r] * al + pp * s2f(kv4[r]);
        }
    }

    float invl = 1.0f / l_i;
    bf16* orow = xout + ((size_t)(b * S_ + s) * H_ + c16) * 256;
#pragma unroll
    for (int n = 0; n < 16; ++n) {
        short4v o;
        o[0] = f2bf_s(acc[n][0] * invl);
        o[1] = f2bf_s(acc[n][1] * invl);
        o[2] = f2bf_s(acc[n][2] * invl);
        o[3] = f2bf_s(acc[n][3] * invl);
        *(short4v*)(void*)&orow[n * 16 + q4 * 4] = o;
    }
}

extern "C" void kernel_launch(void* const* d_in, const int* in_sizes, int n_in,
                              void* d_out, int out_size, void* d_ws, size_t ws_size,
                              hipStream_t stream) {
    const float* hs     = (const float*)d_in[0];
    const float* wq     = (const float*)d_in[1];
    const float* wkv_a  = (const float*)d_in[2];
    const float* ln_g   = (const float*)d_in[3];
    const float* ln_b   = (const float*)d_in[4];
    const float* wkv_b  = (const float*)d_in[5];
    const float* wo     = (const float*)d_in[6];
    const float* fc_c_w = (const float*)d_in[7];
    const float* fc_c_b = (const float*)d_in[8];
    const float* fc_p_w = (const float*)d_in[9];
    const float* fc_p_b = (const float*)d_in[10];
    float* out = (float*)d_out;
    (void)in_sizes; (void)n_in; (void)out_size; (void)ws_size;

    const int M = B_ * S_;  // 4096
    char* wsb = (char*)d_ws;
    size_t o = 0;
    auto alloc = [&](size_t bytes) { char* p = wsb + o; o += (bytes + 255) & ~(size_t)255; return p; };

    bf16* qe = (bf16*)alloc((size_t)M * H_ * 288 * 2);  // 37.75 MB
    char* region2 = alloc((size_t)M * H_ * 256 * 2);    // 33.55 MB
    bf16* hs_bf    = (bf16*)region2;
    bf16* wq_bf    = (bf16*)(region2 + (size_t)M * E_ * 2);
    bf16* wkva_pad = (bf16*)(region2 + (size_t)M * E_ * 2 + (size_t)1536 * E_ * 2);
    bf16* x_bf     = (bf16*)region2;
    char* region3 = alloc((size_t)M * 1536 * 2);        // 12.58 MB
    bf16* q_bf    = (bf16*)region3;
    bf16* outp_bf = (bf16*)region3;
    float* kvraw = (float*)alloc((size_t)M * 384 * 4);
    float* kv_c  = (float*)alloc((size_t)M * 256 * 4);
    float* kpe   = (float*)alloc((size_t)M * 32 * 4);
    bf16* wo_bf   = (bf16*)alloc((size_t)E_ * 1024 * 2);
    bf16* wkvb_bf = (bf16*)alloc((size_t)2048 * 256 * 2);
    bf16* wkvbT   = (bf16*)alloc((size_t)H_ * 256 * 64 * 2);
    bf16* kve_full = (bf16*)alloc((size_t)M * 288 * 2);
    bf16* kvo      = (bf16*)alloc((size_t)B_ * 1024 * 296 * 2);
    bf16* kvoT     = (bf16*)alloc((size_t)B_ * 32 * 8192 * 2);
    float* sscore  = (float*)alloc((size_t)M * H_ * 4);
    float* C2 = (float*)alloc((size_t)S_ * 64 * 4);
    float* P2 = (float*)alloc((size_t)S_ * 64 * 4);
    float* g0 = (float*)alloc(S_ * 4);
    float* g1 = (float*)alloc(S_ * 4);

    // fused conversions (hs, wq, wo, wkv_b, wkva_pad) — one launch
    conv_fused_kernel<<<(CV_N4 + 255) / 256, 256, 0, stream>>>(
        hs, wq, wo, wkv_b, wkv_a, hs_bf, wq_bf, wo_bf, wkvb_bf, wkva_pad);
    transpose_wkvbT_kernel<<<H_, 256, 0, stream>>>(wkv_b, wkvbT);
    // fused projections: q (bf16) + kvraw (f32) in ONE launch (480 blocks)
    gemm_qkv_fused<<<dim3(15, M / 128), 256, 0, stream>>>(hs_bf, wq_bf, wkva_pad, q_bf, kvraw, E_);
    // LN + k_pe rope
    ln_rope_kernel<<<M, 256, 0, stream>>>(kvraw, ln_g, ln_b, kv_c, kpe);
    // gates
    c2p2_kernel<<<S_, 64, 0, stream>>>(fc_c_w, fc_c_b, fc_p_w, fc_p_b, C2, P2);
    gates_kernel<<<(S_ + 255) / 256, 256, 0, stream>>>(C2, P2, g0, g1);
    // kve (full + packed odd) and 32-key tau+XOR-permuted transpose
    kve_kernel<<<M, 256, 0, stream>>>(kv_c, kpe, g0, g1, kve_full, kvo);
    kvoT32_kernel<<<dim3(32, B_), 256, 0, stream>>>(kvo, kvoT);
    // qe = [q_abs * SCALE | rope(q_pe) * SCALE]
    gemm64_lds<bf16><<<dim3(256 / 64, M / 64, H_), 256, 0, stream>>>(
        q_bf, H_ * QKD_, QKD_, wkvbT, 64, 256 * 64, qe, H_ * 288, 288, 64, SCALE_);
    rope_qe_kernel<<<(M * H_ * 16 + 255) / 256, 256, 0, stream>>>(q_bf, qe);
    // self scores
    sscore_kernel<<<dim3(S_, B_), 256, 0, stream>>>(qe, kve_full, sscore);
    // attention (32-key tiles, 4 rows/block, dbuf, XOR-deconflicted PV)
    attn7_kernel<<<dim3(S_ / 4, B_), 256, 0, stream>>>(qe, kvo, kvoT, kve_full, sscore, x_bf);
    // V-projection per head
    gemm64_lds<bf16><<<dim3(1, M / 64, H_), 256, 0, stream>>>(
        x_bf, H_ * 256, 256, wkvb_bf + (size_t)64 * 256, 256, 128 * 256, outp_bf, 1024, 64, 256, 1.0f);
    // final out = outp @ wo^T
    gemm_bt_lds<float><<<dim3(E_ / 128, M / 128), 256, 0, stream>>>(outp_bf, wo_bf, out, M, E_, 1024);
}

// Round 6
// 349.899 us; speedup vs baseline: 1.0665x; 1.0150x over previous
//
#include <hip/hip_runtime.h>
#include <hip/hip_bf16.h>
#include <math.h>
#include <stdint.h>

#define B_ 2
#define S_ 2048
#define E_ 2048
#define H_ 16
#define NOPE_ 64
#define ROPE_ 32
#define V_ 64
#define KVR_ 256
#define QKD_ 96
#define SCALE_ 0.10206207261596577f  /* 96^-0.5 */

typedef __hip_bfloat16 bf16;
typedef __attribute__((ext_vector_type(8))) short short8;
typedef __attribute__((ext_vector_type(4))) short short4v;
typedef __attribute__((ext_vector_type(4))) float floatx4;

__device__ __forceinline__ float bf2f(bf16 v) { return __bfloat162float(v); }
__device__ __forceinline__ float s2f(short v) {
    bf16 h = *reinterpret_cast<bf16*>(&v);
    return __bfloat162float(h);
}
__device__ __forceinline__ short f2bf_s(float f) {
    bf16 h = __float2bfloat16(f);
    return *reinterpret_cast<short*>(&h);
}
__device__ __forceinline__ void store_c(float* C, size_t i, float v) { C[i] = v; }
__device__ __forceinline__ void store_c(bf16* C, size_t i, float v) { C[i] = __float2bfloat16(v); }

// async 16B global -> LDS. Proper addrspacecasts (NO integer truncation — flat LDS
// addresses are aperture-based; C-style cast emits the correct addrspacecast).
__device__ __forceinline__ void g2l16(const bf16* g, bf16* l) {
    __builtin_amdgcn_global_load_lds(
        (const __attribute__((address_space(1))) void*)g,
        (__attribute__((address_space(3))) void*)l,
        16, 0, 0);
}

// ---------------- fused fp32 -> bf16 conversions (hs, wq, wo, wkv_b, wkv_a-pad) ----------
#define CV_N0 1048576              /* hs:    4096*2048/8 */
#define CV_N1 (CV_N0 + 393216)     /* wq:    1536*2048/8 */
#define CV_N2 (CV_N1 + 262144)     /* wo:    2048*1024/8 */
#define CV_N3 (CV_N2 + 65536)      /* wkv_b: 2048*256/8  */
#define CV_N4 (CV_N3 + 98304)      /* wkva_pad: 384*2048/8 */
__global__ __launch_bounds__(256) void conv_fused_kernel(const float* __restrict__ hs,
                                                         const float* __restrict__ wq,
                                                         const float* __restrict__ wo,
                                                         const float* __restrict__ wkv_b,
                                                         const float* __restrict__ wkv_a,
                                                         bf16* __restrict__ hs_bf,
                                                         bf16* __restrict__ wq_bf,
                                                         bf16* __restrict__ wo_bf,
                                                         bf16* __restrict__ wkvb_bf,
                                                         bf16* __restrict__ wkva_pad) {
    int i = blockIdx.x * 256 + threadIdx.x;
    const float* src;
    bf16* dst;
    int j;
    if (i < CV_N0)      { src = hs;    dst = hs_bf;   j = i; }
    else if (i < CV_N1) { src = wq;    dst = wq_bf;   j = i - CV_N0; }
    else if (i < CV_N2) { src = wo;    dst = wo_bf;   j = i - CV_N1; }
    else if (i < CV_N3) { src = wkv_b; dst = wkvb_bf; j = i - CV_N2; }
    else if (i < CV_N4) {
        j = i - CV_N3;
        int row = j >> 8;
        short8 r;
        if (row < 288) {
            float4 a = ((const float4*)wkv_a)[2 * j];
            float4 b = ((const float4*)wkv_a)[2 * j + 1];
            r[0] = f2bf_s(a.x); r[1] = f2bf_s(a.y); r[2] = f2bf_s(a.z); r[3] = f2bf_s(a.w);
            r[4] = f2bf_s(b.x); r[5] = f2bf_s(b.y); r[6] = f2bf_s(b.z); r[7] = f2bf_s(b.w);
        } else {
            for (int k = 0; k < 8; ++k) r[k] = 0;
        }
        ((short8*)wkva_pad)[j] = r;
        return;
    } else return;
    float4 a = ((const float4*)src)[2 * j];
    float4 b = ((const float4*)src)[2 * j + 1];
    short8 r;
    r[0] = f2bf_s(a.x); r[1] = f2bf_s(a.y); r[2] = f2bf_s(a.z); r[3] = f2bf_s(a.w);
    r[4] = f2bf_s(b.x); r[5] = f2bf_s(b.y); r[6] = f2bf_s(b.z); r[7] = f2bf_s(b.w);
    ((short8*)dst)[j] = r;
}

// ---------------- wkvbT[h][c][d] = bf16(wkv_b[h*128+d][c]), d<64 ----------------
// grid = 128 blocks (16 h x 8 d0-chunks): 8x more parallelism than the old 16-block
// version (each thread now does 8 strided loads instead of 64; kernel is latency-bound).
__global__ __launch_bounds__(256) void transpose_wkvbT_kernel(const float* __restrict__ wkv_b,
                                                              bf16* __restrict__ wkvbT) {
    int h = blockIdx.x >> 3;
    int d0 = (blockIdx.x & 7) * 8;
    int c = threadIdx.x;
    short8 v;
#pragma unroll
    for (int j = 0; j < 8; ++j) v[j] = f2bf_s(wkv_b[(size_t)(h * 128 + d0 + j) * 256 + c]);
    *(short8*)(void*)&wkvbT[((size_t)h * 256 + c) * 64 + d0] = v;
}

// ---------------- bf16 MFMA GEMM (m97-style): C(M,N) = A(M,K) @ B(N,K)^T ----------------
// (256,3): m97's structure needs ~164 VGPR; 3 waves/EU caps at 170 -> no spill, but
// guarantees 3 co-resident blocks/CU (LDS is 16KB, never the limit) to hide the
// per-K-step barrier drain.
template <typename TC>
__global__ __launch_bounds__(256, 3) void gemm_bt_lds(const bf16* __restrict__ A,
                                                      const bf16* __restrict__ Bm,
                                                      TC* __restrict__ C,
                                                      int M, int N, int K) {
    __shared__ bf16 Asf[128 * 32];
    __shared__ bf16 Bsf[128 * 32];
    int tid = threadIdx.x;
    int lane = tid & 63, w = tid >> 6;
    int q4 = lane >> 4, c16 = lane & 15;
    int wr = w >> 1, wc = w & 1;
    int m0 = blockIdx.y * 128, n0 = blockIdx.x * 128;
    floatx4 acc[4][4];
#pragma unroll
    for (int mi = 0; mi < 4; ++mi)
#pragma unroll
        for (int ni = 0; ni < 4; ++ni) acc[mi][ni] = (floatx4){0.f, 0.f, 0.f, 0.f};

    for (int k0 = 0; k0 < K; k0 += 32) {
        __syncthreads();
#pragma unroll
        for (int i = 0; i < 2; ++i) {
            int c = (w << 6) + lane + i * 256;
            int row = c >> 2, kc = c & 3;
            g2l16(&A[(size_t)(m0 + row) * K + k0 + kc * 8], &Asf[c * 8]);
            g2l16(&Bm[(size_t)(n0 + row) * K + k0 + kc * 8], &Bsf[c * 8]);
        }
        __syncthreads();
        short8 af[4], bfr[4];
#pragma unroll
        for (int mi = 0; mi < 4; ++mi)
            af[mi] = *(const short8*)(const void*)&Asf[(wr * 64 + mi * 16 + c16) * 32 + q4 * 8];
#pragma unroll
        for (int ni = 0; ni < 4; ++ni)
            bfr[ni] = *(const short8*)(const void*)&Bsf[(wc * 64 + ni * 16 + c16) * 32 + q4 * 8];
#pragma unroll
        for (int mi = 0; mi < 4; ++mi)
#pragma unroll
            for (int ni = 0; ni < 4; ++ni)
                acc[mi][ni] = __builtin_amdgcn_mfma_f32_16x16x32_bf16(af[mi], bfr[ni], acc[mi][ni], 0, 0, 0);
    }
#pragma unroll
    for (int mi = 0; mi < 4; ++mi)
#pragma unroll
        for (int ni = 0; ni < 4; ++ni)
#pragma unroll
            for (int r = 0; r < 4; ++r) {
                int row = m0 + wr * 64 + mi * 16 + q4 * 4 + r;
                int col = n0 + wc * 64 + ni * 16 + c16;
                store_c(C, (size_t)row * N + col, acc[mi][ni][r]);
            }
}

// ---------------- fused projection GEMM: q (bf16 out, N=1536) + kvraw (f32 out, N=384) ---
__global__ __launch_bounds__(256, 3) void gemm_qkv_fused(const bf16* __restrict__ A,
                                                         const bf16* __restrict__ Bq,
                                                         const bf16* __restrict__ Bkv,
                                                         bf16* __restrict__ Cq,
                                                         float* __restrict__ Ckv,
                                                         int K) {
    __shared__ bf16 Asf[128 * 32];
    __shared__ bf16 Bsf[128 * 32];
    int tid = threadIdx.x;
    int lane = tid & 63, w = tid >> 6;
    int q4 = lane >> 4, c16 = lane & 15;
    int wr = w >> 1, wc = w & 1;
    int bx = blockIdx.x;
    bool isq = bx < 12;
    const bf16* Bm = isq ? Bq : Bkv;
    int n0 = isq ? bx * 128 : (bx - 12) * 128;
    int m0 = blockIdx.y * 128;
    floatx4 acc[4][4];
#pragma unroll
    for (int mi = 0; mi < 4; ++mi)
#pragma unroll
        for (int ni = 0; ni < 4; ++ni) acc[mi][ni] = (floatx4){0.f, 0.f, 0.f, 0.f};

    for (int k0 = 0; k0 < K; k0 += 32) {
        __syncthreads();
#pragma unroll
        for (int i = 0; i < 2; ++i) {
            int c = (w << 6) + lane + i * 256;
            int row = c >> 2, kc = c & 3;
            g2l16(&A[(size_t)(m0 + row) * K + k0 + kc * 8], &Asf[c * 8]);
            g2l16(&Bm[(size_t)(n0 + row) * K + k0 + kc * 8], &Bsf[c * 8]);
        }
        __syncthreads();
        short8 af[4], bfr[4];
#pragma unroll
        for (int mi = 0; mi < 4; ++mi)
            af[mi] = *(const short8*)(const void*)&Asf[(wr * 64 + mi * 16 + c16) * 32 + q4 * 8];
#pragma unroll
        for (int ni = 0; ni < 4; ++ni)
            bfr[ni] = *(const short8*)(const void*)&Bsf[(wc * 64 + ni * 16 + c16) * 32 + q4 * 8];
#pragma unroll
        for (int mi = 0; mi < 4; ++mi)
#pragma unroll
            for (int ni = 0; ni < 4; ++ni)
                acc[mi][ni] = __builtin_amdgcn_mfma_f32_16x16x32_bf16(af[mi], bfr[ni], acc[mi][ni], 0, 0, 0);
    }
#pragma unroll
    for (int mi = 0; mi < 4; ++mi)
#pragma unroll
        for (int ni = 0; ni < 4; ++ni)
#pragma unroll
            for (int r = 0; r < 4; ++r) {
                int row = m0 + wr * 64 + mi * 16 + q4 * 4 + r;
                int col = n0 + wc * 64 + ni * 16 + c16;
                if (isq)
                    Cq[(size_t)row * 1536 + col] = __float2bfloat16(acc[mi][ni][r]);
                else
                    Ckv[(size_t)row * 384 + col] = acc[mi][ni][r];
            }
}

// ---------------- small batched bf16 MFMA GEMM (64x64 tiles, global_load_lds) -------------
template <typename TC>
__global__ __launch_bounds__(256, 4) void gemm64_lds(const bf16* __restrict__ A, int lda, int aoffz,
                                                     const bf16* __restrict__ Bm, int ldb, int boffz,
                                                     TC* __restrict__ C, int ldc, int coffz,
                                                     int K, float scale) {
    int z = blockIdx.z;
    A += (size_t)z * aoffz;
    Bm += (size_t)z * boffz;
    C += (size_t)z * coffz;
    __shared__ bf16 Asf[64 * 32];
    __shared__ bf16 Bsf[64 * 32];
    int tid = threadIdx.x;
    int lane = tid & 63, w = tid >> 6;
    int q4 = lane >> 4, c16 = lane & 15;
    int m0 = blockIdx.y * 64, n0 = blockIdx.x * 64;
    floatx4 acc[4];
#pragma unroll
    for (int ni = 0; ni < 4; ++ni) acc[ni] = (floatx4){0.f, 0.f, 0.f, 0.f};
    int row = tid >> 2, kc = tid & 3;
    for (int k0 = 0; k0 < K; k0 += 32) {
        __syncthreads();
        g2l16(&A[(size_t)(m0 + row) * lda + k0 + kc * 8], &Asf[tid * 8]);
        g2l16(&Bm[(size_t)(n0 + row) * ldb + k0 + kc * 8], &Bsf[tid * 8]);
        __syncthreads();
        short8 af = *(const short8*)(const void*)&Asf[(w * 16 + c16) * 32 + q4 * 8];
#pragma unroll
        for (int ni = 0; ni < 4; ++ni) {
            short8 bfr = *(const short8*)(const void*)&Bsf[(ni * 16 + c16) * 32 + q4 * 8];
            acc[ni] = __builtin_amdgcn_mfma_f32_16x16x32_bf16(af, bfr, acc[ni], 0, 0, 0);
        }
    }
#pragma unroll
    for (int ni = 0; ni < 4; ++ni)
#pragma unroll
        for (int rr = 0; rr < 4; ++rr)
            store_c(C, (size_t)(m0 + w * 16 + q4 * 4 + rr) * ldc + n0 + ni * 16 + c16,
                    acc[ni][rr] * scale);
}

// ---------------- LayerNorm(kv_c) + RoPE(k_pe); input stride 384 ----------------
__global__ __launch_bounds__(256) void ln_rope_kernel(const float* __restrict__ kvraw,
                                                      const float* __restrict__ g,
                                                      const float* __restrict__ bta,
                                                      float* __restrict__ kv_c,
                                                      float* __restrict__ kpe) {
    int r = blockIdx.x;
    int tid = threadIdx.x;
    int lane = tid & 63, w = tid >> 6;
    float x = kvraw[(size_t)r * 384 + tid];
    float v1 = x, v2 = x * x;
#pragma unroll
    for (int o = 32; o; o >>= 1) { v1 += __shfl_down(v1, o); v2 += __shfl_down(v2, o); }
    __shared__ float s1[4], s2[4], stats[2];
    if (lane == 0) { s1[w] = v1; s2[w] = v2; }
    __syncthreads();
    if (tid == 0) {
        float S1 = s1[0] + s1[1] + s1[2] + s1[3];
        float S2 = s2[0] + s2[1] + s2[2] + s2[3];
        float mean = S1 / 256.0f;
        float var = S2 / 256.0f - mean * mean;
        stats[0] = mean;
        stats[1] = rsqrtf(var + 1e-5f);
    }
    __syncthreads();
    float y = (x - stats[0]) * stats[1] * g[tid] + bta[tid];
    kv_c[(size_t)r * 256 + tid] = y;
    if (tid < 16) {
        int j = tid;
        int s = r & (S_ - 1);
        float freq = expf(-(float)(2 * j) * 0.28782313662425572f);  // ln(1e4)/32
        float ang = (float)s * freq;
        float c = cosf(ang), sn = sinf(ang);
        float x0 = kvraw[(size_t)r * 384 + 256 + 2 * j];
        float x1 = kvraw[(size_t)r * 384 + 256 + 2 * j + 1];
        kpe[(size_t)r * 32 + 2 * j]     = x0 * c - x1 * sn;
        kpe[(size_t)r * 32 + 2 * j + 1] = x0 * sn + x1 * c;
    }
}

// ---------------- C2 / P2 ----------------
__global__ __launch_bounds__(64) void c2p2_kernel(const float* __restrict__ fcw_c,
                                                  const float* __restrict__ fcb_c,
                                                  const float* __restrict__ fcw_p,
                                                  const float* __restrict__ fcb_p,
                                                  float* __restrict__ C2,
                                                  float* __restrict__ P2) {
    int t = blockIdx.x;
    int k = threadIdx.x;
    __shared__ float Crow[256], Prow[256];
    for (int i = k; i < 128; i += 64) {
        float div = expf(-(float)i * 0.07195578415606393f);  // ln(1e4)/128
        float ap = (float)t * div;
        Prow[2 * i]     = sinf(ap);
        Prow[2 * i + 1] = cosf(ap);
        float ac = (float)(t >> 1) * div;
        Crow[2 * i]     = sinf(ac);
        Crow[2 * i + 1] = cosf(ac);
    }
    __syncthreads();
    float sc = fcb_c[k], sp = fcb_p[k];
    for (int c = 0; c < 256; ++c) {
        sc += Crow[c] * fcw_c[(size_t)k * 256 + c];
        sp += Prow[c] * fcw_p[(size_t)k * 256 + c];
    }
    C2[(size_t)t * 64 + k] = sc;
    P2[(size_t)t * 64 + k] = sp;
}

__global__ __launch_bounds__(256) void gates_kernel(const float* __restrict__ C2,
                                                    const float* __restrict__ P2,
                                                    float* __restrict__ g0,
                                                    float* __restrict__ g1) {
    int t = blockIdx.x * 256 + threadIdx.x;
    if (t >= S_) return;
    float d0 = 0.f;
    for (int k = 0; k < 64; ++k) d0 += C2[(size_t)t * 64 + k] * P2[(size_t)t * 64 + k];
    g0[t] = 1.0f / (1.0f + expf(-d0));
    float gg = 0.f;
    if (t & 1) {
        float d1 = 0.f;
        for (int k = 0; k < 64; ++k) d1 += C2[(size_t)t * 64 + k] * P2[(size_t)(t - 1) * 64 + k];
        gg = 1.0f / (1.0f + expf(-d1));
    }
    g1[t] = gg;
}

// ---------------- gated kv_t -> kve_full [B*S][288] + packed odd kvo [B][1024][296] ------
__global__ __launch_bounds__(256) void kve_kernel(const float* __restrict__ kv_c,
                                                  const float* __restrict__ kpe,
                                                  const float* __restrict__ g0,
                                                  const float* __restrict__ g1,
                                                  bf16* __restrict__ kve_full,
                                                  bf16* __restrict__ kvo) {
    int r = blockIdx.x, tid = threadIdx.x;
    int b = r >> 11, t = r & (S_ - 1);
    float a = g0[t], bb = g1[t];
    float v = a * kv_c[(size_t)r * 256 + tid];
    if (t & 1) v += bb * kv_c[(size_t)(r - 1) * 256 + tid];
    bf16 vb = __float2bfloat16(v);
    kve_full[(size_t)r * 288 + tid] = vb;
    if (t & 1) kvo[((size_t)b * 1024 + (t >> 1)) * 296 + tid] = vb;
    if (tid < 32) {
        float u = a * kpe[(size_t)r * 32 + tid];
        if (t & 1) u += bb * kpe[(size_t)(r - 1) * 32 + tid];
        bf16 ub = __float2bfloat16(u);
        kve_full[(size_t)r * 288 + 256 + tid] = ub;
        if (t & 1) kvo[((size_t)b * 1024 + (t >> 1)) * 296 + 256 + tid] = ub;
    }
}

// ---------------- kvoT32[b][uch][c][chunk] = kvo[b][uch*32 + tau(kslot)][c] --------------
// tau(8q+j) = (j<4) ? 4q+j : 16 + 4q + (j-4): makes the score C-layout line up
// register-for-slot with the 16x16x32 PV B-fragment. ADDITIONALLY the four 16B chunks of
// each c-row are stored XOR-swizzled (chunk' = chunk ^ ((c>>1)&3)) so that the linear
// global_load_lds staging lands a bank-conflict-free layout; the attn PV read applies
// the same XOR. (HW-verified in R4/R5: conflicts 9.19M -> 4.87M on the 1024-block grid.)
__global__ __launch_bounds__(256) void kvoT32_kernel(const bf16* __restrict__ kvo,
                                                     bf16* __restrict__ kvoT) {
    int uch = blockIdx.x, b = blockIdx.y;
    int c = threadIdx.x;
    const bf16* src = kvo + ((size_t)b * 1024 + uch * 32) * 296 + c;
    short v[32];
#pragma unroll
    for (int j = 0; j < 32; ++j) v[j] = *(const short*)&src[(size_t)j * 296];
    bf16* dst = kvoT + (((size_t)b * 32 + uch) * 256 + c) * 32;
    int swz = (c >> 1) & 3;
#pragma unroll
    for (int q = 0; q < 4; ++q) {
        short8 o;
#pragma unroll
        for (int jj = 0; jj < 8; ++jj)
            o[jj] = (jj < 4) ? v[4 * q + jj] : v[16 + 4 * q + (jj - 4)];
        *(short8*)(void*)&dst[(q ^ swz) * 8] = o;
    }
}

// ---------------- roped, scaled q_pe -> qe[...,256:288) ----------------
__global__ __launch_bounds__(256) void rope_qe_kernel(const bf16* __restrict__ q,
                                                      bf16* __restrict__ qe) {
    int idx = blockIdx.x * 256 + threadIdx.x;
    if (idx >= B_ * S_ * H_ * 16) return;
    int j = idx & 15;
    int s = (idx >> 8) & (S_ - 1);
    float freq = expf(-(float)(2 * j) * 0.28782313662425572f);
    float ang = (float)s * freq;
    float c = cosf(ang), sn = sinf(ang);
    size_t row = idx >> 4;
    float a0 = bf2f(q[row * QKD_ + NOPE_ + 2 * j]);
    float a1 = bf2f(q[row * QKD_ + NOPE_ + 2 * j + 1]);
    qe[row * 288 + 256 + 2 * j]     = __float2bfloat16((a0 * c - a1 * sn) * SCALE_);
    qe[row * 288 + 256 + 2 * j + 1] = __float2bfloat16((a0 * sn + a1 * c) * SCALE_);
}

// ---------------- flash attention: 32-key tiles, dbuf, XOR-swizzled PV, fused sscore -----
// attn7 structure (best measured) + in-kernel self-score: selfr holds the full 288-dim
// kve row; each wave computes dot(qf, selfr[w]) with 72 FMA + 2 shfl — removes the
// separate sscore kernel and its 38MB qe re-read.
__global__ __launch_bounds__(256, 2) void attn8_kernel(const bf16* __restrict__ qe,
                                                       const bf16* __restrict__ kvo,
                                                       const bf16* __restrict__ kvoT,
                                                       const bf16* __restrict__ kve_full,
                                                       bf16* __restrict__ xout) {
    int s0 = (int)(gridDim.x - 1 - blockIdx.x) * 4;  // biggest blocks first
    int b = blockIdx.y;
    int tid = threadIdx.x;
    int lane = tid & 63, w = tid >> 6;
    int q4 = lane >> 4, c16 = lane & 15;
    int s = s0 + w;
    int Nodd = (s + 1) >> 1;
    int NoddMax = (s0 + 4) >> 1;
    int niter = (NoddMax + 31) >> 5;

    __shared__ bf16 kvos[2][32][296];   // 2 x 18944 B: score-side K rows
    __shared__ bf16 kvts[2][256][32];   // 2 x 16384 B: PV-side V tile (tau+XOR layout)
    __shared__ bf16 selfr[4][288];      // self-key kv rows, FULL 288 channels

    const bf16* kvob = kvo + (size_t)b * 1024 * 296;
    const bf16* kvoTb = kvoT + (size_t)b * 32 * 8192;

    if (tid < 144) {
        int rr = tid / 36, ch = tid - rr * 36;
        *(short8*)(void*)&selfr[rr][ch * 8] =
            *(const short8*)(const void*)&kve_full[(size_t)(b * S_ + s0 + rr) * 288 + ch * 8];
    }

    short8 qf[9];
    const bf16* qrow = qe + ((size_t)(b * S_ + s) * H_ + c16) * 288;
#pragma unroll
    for (int kk = 0; kk < 9; ++kk) qf[kk] = *(const short8*)(const void*)&qrow[kk * 32 + q4 * 8];

    floatx4 acc[16];
#pragma unroll
    for (int n = 0; n < 16; ++n) acc[n] = (floatx4){0.f, 0.f, 0.f, 0.f};
    float m_i = -1e30f, l_i = 0.f;
    int swz = (c16 >> 1) & 3;  // PV chunk XOR (matches kvoT32 writer)

    // async stage of tile t into buffer p: kvos = 1184 16B chunks, kvts = 1024 16B chunks
    auto stage = [&](int t, int p) {
        const bf16* sa = kvob + (size_t)t * 32 * 296;
        bf16* la = &kvos[p][0][0];
#pragma unroll
        for (int i = 0; i < 4; ++i)
            g2l16(&sa[(size_t)(tid + i * 256) * 8], &la[(size_t)(tid + i * 256) * 8]);
        if (tid < 160) g2l16(&sa[(size_t)(tid + 1024) * 8], &la[(size_t)(tid + 1024) * 8]);
        const bf16* sb = kvoTb + (size_t)t * 8192;
        bf16* lb = &kvts[p][0][0];
#pragma unroll
        for (int i = 0; i < 4; ++i)
            g2l16(&sb[(size_t)(tid + i * 256) * 8], &lb[(size_t)(tid + i * 256) * 8]);
    };

    stage(0, 0);
    __syncthreads();  // prologue drain (also makes selfr visible)

    // in-register self score: sscore(b,s,h=c16) = dot(qe_row(s,h), kve_row(s)).
    // Each lane holds 72 of 288 q elems (q4 partition); reduce over q4 via shfl.
    float sdot = 0.f;
#pragma unroll
    for (int kk = 0; kk < 9; ++kk) {
        short8 kv8 = *(const short8*)(const void*)&selfr[w][kk * 32 + q4 * 8];
#pragma unroll
        for (int j = 0; j < 8; ++j) sdot += s2f(qf[kk][j]) * s2f(kv8[j]);
    }
    sdot += __shfl_xor(sdot, 16);
    sdot += __shfl_xor(sdot, 32);

    for (int it = 0; it < niter; ++it) {
        int p = it & 1;
        // Issue next tile's loads FIRST — they land during this iteration's compute.
        if (it + 1 < niter) stage(it + 1, 1 - p);

        int u0 = it * 32;
        // scores^T for 32 keys: tile A = rows c16 (keys u0+4q4+r), tile B = rows 16+c16.
        floatx4 ca0 = (floatx4){0.f, 0.f, 0.f, 0.f}, ca1 = (floatx4){0.f, 0.f, 0.f, 0.f};
        floatx4 cb0 = (floatx4){0.f, 0.f, 0.f, 0.f}, cb1 = (floatx4){0.f, 0.f, 0.f, 0.f};
        __builtin_amdgcn_s_setprio(1);
#pragma unroll
        for (int kk = 0; kk < 9; ++kk) {
            short8 avA = *(const short8*)(const void*)&kvos[p][c16][kk * 32 + q4 * 8];
            short8 avB = *(const short8*)(const void*)&kvos[p][16 + c16][kk * 32 + q4 * 8];
            if (kk & 1) {
                ca1 = __builtin_amdgcn_mfma_f32_16x16x32_bf16(avA, qf[kk], ca1, 0, 0, 0);
                cb1 = __builtin_amdgcn_mfma_f32_16x16x32_bf16(avB, qf[kk], cb1, 0, 0, 0);
            } else {
                ca0 = __builtin_amdgcn_mfma_f32_16x16x32_bf16(avA, qf[kk], ca0, 0, 0, 0);
                cb0 = __builtin_amdgcn_mfma_f32_16x16x32_bf16(avB, qf[kk], cb0, 0, 0, 0);
            }
        }
        __builtin_amdgcn_s_setprio(0);
        floatx4 cA = ca0 + ca1;
        floatx4 cB = cb0 + cb1;
        int kA = u0 + q4 * 4;
        int kB = u0 + 16 + q4 * 4;
#pragma unroll
        for (int r = 0; r < 4; ++r) {
            if (kA + r >= Nodd) cA[r] = -1e30f;
            if (kB + r >= Nodd) cB[r] = -1e30f;
        }
        float tmax = fmaxf(fmaxf(fmaxf(cA[0], cA[1]), fmaxf(cA[2], cA[3])),
                           fmaxf(fmaxf(cB[0], cB[1]), fmaxf(cB[2], cB[3])));
        tmax = fmaxf(tmax, __shfl_xor(tmax, 16));
        tmax = fmaxf(tmax, __shfl_xor(tmax, 32));
        float mn = fmaxf(m_i, tmax);
        bool chg = mn > m_i;
        float al = __expf(m_i - mn);
        float pA0 = __expf(cA[0] - mn), pA1 = __expf(cA[1] - mn);
        float pA2 = __expf(cA[2] - mn), pA3 = __expf(cA[3] - mn);
        float pB0 = __expf(cB[0] - mn), pB1 = __expf(cB[1] - mn);
        float pB2 = __expf(cB[2] - mn), pB3 = __expf(cB[3] - mn);
        float rs = (pA0 + pA1 + pA2 + pA3) + (pB0 + pB1 + pB2 + pB3);
        rs += __shfl_xor(rs, 16);
        rs += __shfl_xor(rs, 32);
        l_i = l_i * al + rs;
        m_i = mn;
        if (__any(chg)) {
#pragma unroll
            for (int n = 0; n < 16; ++n) {
                acc[n][0] *= al; acc[n][1] *= al; acc[n][2] *= al; acc[n][3] *= al;
            }
        }
        // PV with 16x16x32: B-frag k-slot q4*8+j maps to key tau(q4*8+j); kvts stores V
        // in the same tau order; chunk XOR de-conflicts the read.
        short8 pf;
        pf[0] = f2bf_s(pA0); pf[1] = f2bf_s(pA1); pf[2] = f2bf_s(pA2); pf[3] = f2bf_s(pA3);
        pf[4] = f2bf_s(pB0); pf[5] = f2bf_s(pB1); pf[6] = f2bf_s(pB2); pf[7] = f2bf_s(pB3);
        __builtin_amdgcn_s_setprio(1);
#pragma unroll
        for (int n = 0; n < 16; ++n) {
            short8 a8 = *(const short8*)(const void*)&kvts[p][n * 16 + c16][(q4 ^ swz) * 8];
            acc[n] = __builtin_amdgcn_mfma_f32_16x16x32_bf16(a8, pf, acc[n], 0, 0, 0);
        }
        __builtin_amdgcn_s_setprio(0);
        // ONE barrier per iteration: (a) all waves done reading buffer p;
        // (b) implicit vmcnt(0) drain makes tile it+1 (issued at iter start) visible.
        __syncthreads();
    }

    // self key (even s; odd s already included in odd set)
    if ((s & 1) == 0) {
        float mn = fmaxf(m_i, sdot);
        float al = __expf(m_i - mn);
        float pp = __expf(sdot - mn);
        l_i = l_i * al + pp;
        m_i = mn;
#pragma unroll
        for (int n = 0; n < 16; ++n) {
            short4v kv4 = *(const short4v*)(const void*)&selfr[w][n * 16 + q4 * 4];
#pragma unroll
            for (int r = 0; r < 4; ++r)
                acc[n][r] = acc[n][r] * al + pp * s2f(kv4[r]);
        }
    }

    float invl = 1.0f / l_i;
    bf16* orow = xout + ((size_t)(b * S_ + s) * H_ + c16) * 256;
#pragma unroll
    for (int n = 0; n < 16; ++n) {
        short4v o;
        o[0] = f2bf_s(acc[n][0] * invl);
        o[1] = f2bf_s(acc[n][1] * invl);
        o[2] = f2bf_s(acc[n][2] * invl);
        o[3] = f2bf_s(acc[n][3] * invl);
        *(short4v*)(void*)&orow[n * 16 + q4 * 4] = o;
    }
}

extern "C" void kernel_launch(void* const* d_in, const int* in_sizes, int n_in,
                              void* d_out, int out_size, void* d_ws, size_t ws_size,
                              hipStream_t stream) {
    const float* hs     = (const float*)d_in[0];
    const float* wq     = (const float*)d_in[1];
    const float* wkv_a  = (const float*)d_in[2];
    const float* ln_g   = (const float*)d_in[3];
    const float* ln_b   = (const float*)d_in[4];
    const float* wkv_b  = (const float*)d_in[5];
    const float* wo     = (const float*)d_in[6];
    const float* fc_c_w = (const float*)d_in[7];
    const float* fc_c_b = (const float*)d_in[8];
    const float* fc_p_w = (const float*)d_in[9];
    const float* fc_p_b = (const float*)d_in[10];
    float* out = (float*)d_out;
    (void)in_sizes; (void)n_in; (void)out_size; (void)ws_size;

    const int M = B_ * S_;  // 4096
    char* wsb = (char*)d_ws;
    size_t o = 0;
    auto alloc = [&](size_t bytes) { char* p = wsb + o; o += (bytes + 255) & ~(size_t)255; return p; };

    bf16* qe = (bf16*)alloc((size_t)M * H_ * 288 * 2);  // 37.75 MB
    char* region2 = alloc((size_t)M * H_ * 256 * 2);    // 33.55 MB
    bf16* hs_bf    = (bf16*)region2;
    bf16* wq_bf    = (bf16*)(region2 + (size_t)M * E_ * 2);
    bf16* wkva_pad = (bf16*)(region2 + (size_t)M * E_ * 2 + (size_t)1536 * E_ * 2);
    bf16* x_bf     = (bf16*)region2;
    char* region3 = alloc((size_t)M * 1536 * 2);        // 12.58 MB
    bf16* q_bf    = (bf16*)region3;
    bf16* outp_bf = (bf16*)region3;
    float* kvraw = (float*)alloc((size_t)M * 384 * 4);
    float* kv_c  = (float*)alloc((size_t)M * 256 * 4);
    float* kpe   = (float*)alloc((size_t)M * 32 * 4);
    bf16* wo_bf   = (bf16*)alloc((size_t)E_ * 1024 * 2);
    bf16* wkvb_bf = (bf16*)alloc((size_t)2048 * 256 * 2);
    bf16* wkvbT   = (bf16*)alloc((size_t)H_ * 256 * 64 * 2);
    bf16* kve_full = (bf16*)alloc((size_t)M * 288 * 2);
    bf16* kvo      = (bf16*)alloc((size_t)B_ * 1024 * 296 * 2);
    bf16* kvoT     = (bf16*)alloc((size_t)B_ * 32 * 8192 * 2);
    float* C2 = (float*)alloc((size_t)S_ * 64 * 4);
    float* P2 = (float*)alloc((size_t)S_ * 64 * 4);
    float* g0 = (float*)alloc(S_ * 4);
    float* g1 = (float*)alloc(S_ * 4);

    // fused conversions (hs, wq, wo, wkv_b, wkva_pad) — one launch
    conv_fused_kernel<<<(CV_N4 + 255) / 256, 256, 0, stream>>>(
        hs, wq, wo, wkv_b, wkv_a, hs_bf, wq_bf, wo_bf, wkvb_bf, wkva_pad);
    transpose_wkvbT_kernel<<<H_ * 8, 256, 0, stream>>>(wkv_b, wkvbT);
    // fused projections: q (bf16) + kvraw (f32) in ONE launch (480 blocks)
    gemm_qkv_fused<<<dim3(15, M / 128), 256, 0, stream>>>(hs_bf, wq_bf, wkva_pad, q_bf, kvraw, E_);
    // LN + k_pe rope
    ln_rope_kernel<<<M, 256, 0, stream>>>(kvraw, ln_g, ln_b, kv_c, kpe);
    // gates
    c2p2_kernel<<<S_, 64, 0, stream>>>(fc_c_w, fc_c_b, fc_p_w, fc_p_b, C2, P2);
    gates_kernel<<<(S_ + 255) / 256, 256, 0, stream>>>(C2, P2, g0, g1);
    // kve (full + packed odd) and 32-key tau+XOR-permuted transpose
    kve_kernel<<<M, 256, 0, stream>>>(kv_c, kpe, g0, g1, kve_full, kvo);
    kvoT32_kernel<<<dim3(32, B_), 256, 0, stream>>>(kvo, kvoT);
    // qe = [q_abs * SCALE | rope(q_pe) * SCALE]
    gemm64_lds<bf16><<<dim3(256 / 64, M / 64, H_), 256, 0, stream>>>(
        q_bf, H_ * QKD_, QKD_, wkvbT, 64, 256 * 64, qe, H_ * 288, 288, 64, SCALE_);
    rope_qe_kernel<<<(M * H_ * 16 + 255) / 256, 256, 0, stream>>>(q_bf, qe);
    // attention (32-key tiles, dbuf, XOR-deconflicted PV, fused self-score)
    attn8_kernel<<<dim3(S_ / 4, B_), 256, 0, stream>>>(qe, kvo, kvoT, kve_full, x_bf);
    // V-projection per head
    gemm64_lds<bf16><<<dim3(1, M / 64, H_), 256, 0, stream>>>(
        x_bf, H_ * 256, 256, wkvb_bf + (size_t)64 * 256, 256, 128 * 256, outp_bf, 1024, 64, 256, 1.0f);
    // final out = outp @ wo^T
    gemm_bt_lds<float><<<dim3(E_ / 128, M / 128), 256, 0, stream>>>(outp_bf, wo_bf, out, M, E_, 1024);
}

// Round 7
// 338.497 us; speedup vs baseline: 1.1024x; 1.0337x over previous
//
#include <hip/hip_runtime.h>
#include <hip/hip_bf16.h>
#include <math.h>
#include <stdint.h>

#define B_ 2
#define S_ 2048
#define E_ 2048
#define H_ 16
#define NOPE_ 64
#define ROPE_ 32
#define V_ 64
#define KVR_ 256
#define QKD_ 96
#define SCALE_ 0.10206207261596577f  /* 96^-0.5 */

typedef __hip_bfloat16 bf16;
typedef __attribute__((ext_vector_type(8))) short short8;
typedef __attribute__((ext_vector_type(4))) short short4v;
typedef __attribute__((ext_vector_type(4))) float floatx4;

__device__ __forceinline__ float bf2f(bf16 v) { return __bfloat162float(v); }
__device__ __forceinline__ float s2f(short v) {
    bf16 h = *reinterpret_cast<bf16*>(&v);
    return __bfloat162float(h);
}
__device__ __forceinline__ short f2bf_s(float f) {
    bf16 h = __float2bfloat16(f);
    return *reinterpret_cast<short*>(&h);
}
__device__ __forceinline__ void store_c(float* C, size_t i, float v) { C[i] = v; }
__device__ __forceinline__ void store_c(bf16* C, size_t i, float v) { C[i] = __float2bfloat16(v); }

// async 16B global -> LDS. Proper addrspacecasts (NO integer truncation — flat LDS
// addresses are aperture-based; C-style cast emits the correct addrspacecast).
__device__ __forceinline__ void g2l16(const bf16* g, bf16* l) {
    __builtin_amdgcn_global_load_lds(
        (const __attribute__((address_space(1))) void*)g,
        (__attribute__((address_space(3))) void*)l,
        16, 0, 0);
}

// ---------------- fused fp32 -> bf16 conversions + wkvbT transpose -----------------------
// Segments: hs, wq, wo, wkv_b, wkva_pad (zero-padded), wkvbT (transposed). All segment
// boundaries are multiples of 256 work items -> every block takes exactly one branch.
#define CV_N0 1048576              /* hs:    4096*2048/8 */
#define CV_N1 (CV_N0 + 393216)     /* wq:    1536*2048/8 */
#define CV_N2 (CV_N1 + 262144)     /* wo:    2048*1024/8 */
#define CV_N3 (CV_N2 + 65536)      /* wkv_b: 2048*256/8  */
#define CV_N4 (CV_N3 + 98304)      /* wkva_pad: 384*2048/8 */
#define CV_N5 (CV_N4 + 32768)      /* wkvbT: 16h x 8 d0-chunks x 256 c */
__global__ __launch_bounds__(256) void conv_fused_kernel(const float* __restrict__ hs,
                                                         const float* __restrict__ wq,
                                                         const float* __restrict__ wo,
                                                         const float* __restrict__ wkv_b,
                                                         const float* __restrict__ wkv_a,
                                                         bf16* __restrict__ hs_bf,
                                                         bf16* __restrict__ wq_bf,
                                                         bf16* __restrict__ wo_bf,
                                                         bf16* __restrict__ wkvb_bf,
                                                         bf16* __restrict__ wkva_pad,
                                                         bf16* __restrict__ wkvbT) {
    int i = blockIdx.x * 256 + threadIdx.x;
    const float* src;
    bf16* dst;
    int j;
    if (i < CV_N0)      { src = hs;    dst = hs_bf;   j = i; }
    else if (i < CV_N1) { src = wq;    dst = wq_bf;   j = i - CV_N0; }
    else if (i < CV_N2) { src = wo;    dst = wo_bf;   j = i - CV_N1; }
    else if (i < CV_N3) { src = wkv_b; dst = wkvb_bf; j = i - CV_N2; }
    else if (i < CV_N4) {
        j = i - CV_N3;
        int row = j >> 8;
        short8 r;
        if (row < 288) {
            float4 a = ((const float4*)wkv_a)[2 * j];
            float4 b = ((const float4*)wkv_a)[2 * j + 1];
            r[0] = f2bf_s(a.x); r[1] = f2bf_s(a.y); r[2] = f2bf_s(a.z); r[3] = f2bf_s(a.w);
            r[4] = f2bf_s(b.x); r[5] = f2bf_s(b.y); r[6] = f2bf_s(b.z); r[7] = f2bf_s(b.w);
        } else {
            for (int k = 0; k < 8; ++k) r[k] = 0;
        }
        ((short8*)wkva_pad)[j] = r;
        return;
    } else if (i < CV_N5) {
        j = i - CV_N4;
        int h = j >> 11;
        int rem = j & 2047;
        int d0 = (rem >> 8) * 8;
        int c = rem & 255;
        short8 v;
#pragma unroll
        for (int jj = 0; jj < 8; ++jj)
            v[jj] = f2bf_s(wkv_b[(size_t)(h * 128 + d0 + jj) * 256 + c]);
        *(short8*)(void*)&wkvbT[((size_t)h * 256 + c) * 64 + d0] = v;
        return;
    } else return;
    float4 a = ((const float4*)src)[2 * j];
    float4 b = ((const float4*)src)[2 * j + 1];
    short8 r;
    r[0] = f2bf_s(a.x); r[1] = f2bf_s(a.y); r[2] = f2bf_s(a.z); r[3] = f2bf_s(a.w);
    r[4] = f2bf_s(b.x); r[5] = f2bf_s(b.y); r[6] = f2bf_s(b.z); r[7] = f2bf_s(b.w);
    ((short8*)dst)[j] = r;
}

// ---------------- bf16 MFMA GEMM (m97-style): C(M,N) = A(M,K) @ B(N,K)^T ----------------
template <typename TC>
__global__ __launch_bounds__(256, 2) void gemm_bt_lds(const bf16* __restrict__ A,
                                                      const bf16* __restrict__ Bm,
                                                      TC* __restrict__ C,
                                                      int M, int N, int K) {
    __shared__ bf16 Asf[128 * 32];
    __shared__ bf16 Bsf[128 * 32];
    int tid = threadIdx.x;
    int lane = tid & 63, w = tid >> 6;
    int q4 = lane >> 4, c16 = lane & 15;
    int wr = w >> 1, wc = w & 1;
    int m0 = blockIdx.y * 128, n0 = blockIdx.x * 128;
    floatx4 acc[4][4];
#pragma unroll
    for (int mi = 0; mi < 4; ++mi)
#pragma unroll
        for (int ni = 0; ni < 4; ++ni) acc[mi][ni] = (floatx4){0.f, 0.f, 0.f, 0.f};

    for (int k0 = 0; k0 < K; k0 += 32) {
        __syncthreads();
#pragma unroll
        for (int i = 0; i < 2; ++i) {
            int c = (w << 6) + lane + i * 256;
            int row = c >> 2, kc = c & 3;
            g2l16(&A[(size_t)(m0 + row) * K + k0 + kc * 8], &Asf[c * 8]);
            g2l16(&Bm[(size_t)(n0 + row) * K + k0 + kc * 8], &Bsf[c * 8]);
        }
        __syncthreads();
        short8 af[4], bfr[4];
#pragma unroll
        for (int mi = 0; mi < 4; ++mi)
            af[mi] = *(const short8*)(const void*)&Asf[(wr * 64 + mi * 16 + c16) * 32 + q4 * 8];
#pragma unroll
        for (int ni = 0; ni < 4; ++ni)
            bfr[ni] = *(const short8*)(const void*)&Bsf[(wc * 64 + ni * 16 + c16) * 32 + q4 * 8];
#pragma unroll
        for (int mi = 0; mi < 4; ++mi)
#pragma unroll
            for (int ni = 0; ni < 4; ++ni)
                acc[mi][ni] = __builtin_amdgcn_mfma_f32_16x16x32_bf16(af[mi], bfr[ni], acc[mi][ni], 0, 0, 0);
    }
#pragma unroll
    for (int mi = 0; mi < 4; ++mi)
#pragma unroll
        for (int ni = 0; ni < 4; ++ni)
#pragma unroll
            for (int r = 0; r < 4; ++r) {
                int row = m0 + wr * 64 + mi * 16 + q4 * 4 + r;
                int col = n0 + wc * 64 + ni * 16 + c16;
                store_c(C, (size_t)row * N + col, acc[mi][ni][r]);
            }
}

// ---------------- fused projection GEMM, 64x128 tiles: q (bf16, N=1536) + kvraw (f32) ----
// 960 blocks (was 480 @128^2): ~32-VGPR accumulators -> many schedulable waves/SIMD,
// 3.75 blocks/CU, finer tail. 1D grid with bijective XCD swizzle (960 % 8 == 0).
__global__ __launch_bounds__(256) void gemm_qkv_fused64(const bf16* __restrict__ A,
                                                        const bf16* __restrict__ Bq,
                                                        const bf16* __restrict__ Bkv,
                                                        bf16* __restrict__ Cq,
                                                        float* __restrict__ Ckv,
                                                        int K) {
    int bid = blockIdx.x;
    int orig = (bid & 7) * 120 + (bid >> 3);  // XCD-chunked: each XCD gets 120 consecutive
    int by = orig / 15, bx = orig % 15;
    bool isq = bx < 12;
    const bf16* Bm = isq ? Bq : Bkv;
    int n0 = isq ? bx * 128 : (bx - 12) * 128;
    int m0 = by * 64;
    __shared__ bf16 Asf[64 * 32];
    __shared__ bf16 Bsf[128 * 32];
    int tid = threadIdx.x;
    int lane = tid & 63, w = tid >> 6;
    int q4 = lane >> 4, c16 = lane & 15;
    int wr = w >> 1, wc = w & 1;  // wave covers rows wr*32..+32, cols wc*64..+64
    floatx4 acc[2][4];
#pragma unroll
    for (int mi = 0; mi < 2; ++mi)
#pragma unroll
        for (int ni = 0; ni < 4; ++ni) acc[mi][ni] = (floatx4){0.f, 0.f, 0.f, 0.f};

    for (int k0 = 0; k0 < K; k0 += 32) {
        __syncthreads();
        {
            int c = tid;  // A: 256 chunks, 1/thread
            int row = c >> 2, kc = c & 3;
            g2l16(&A[(size_t)(m0 + row) * K + k0 + kc * 8], &Asf[c * 8]);
        }
#pragma unroll
        for (int i = 0; i < 2; ++i) {  // B: 512 chunks, 2/thread
            int c = tid + i * 256;
            int row = c >> 2, kc = c & 3;
            g2l16(&Bm[(size_t)(n0 + row) * K + k0 + kc * 8], &Bsf[c * 8]);
        }
        __syncthreads();
        short8 af[2], bfr[4];
#pragma unroll
        for (int mi = 0; mi < 2; ++mi)
            af[mi] = *(const short8*)(const void*)&Asf[(wr * 32 + mi * 16 + c16) * 32 + q4 * 8];
#pragma unroll
        for (int ni = 0; ni < 4; ++ni)
            bfr[ni] = *(const short8*)(const void*)&Bsf[(wc * 64 + ni * 16 + c16) * 32 + q4 * 8];
#pragma unroll
        for (int mi = 0; mi < 2; ++mi)
#pragma unroll
            for (int ni = 0; ni < 4; ++ni)
                acc[mi][ni] = __builtin_amdgcn_mfma_f32_16x16x32_bf16(af[mi], bfr[ni], acc[mi][ni], 0, 0, 0);
    }
#pragma unroll
    for (int mi = 0; mi < 2; ++mi)
#pragma unroll
        for (int ni = 0; ni < 4; ++ni)
#pragma unroll
            for (int r = 0; r < 4; ++r) {
                int row = m0 + wr * 32 + mi * 16 + q4 * 4 + r;
                int col = n0 + wc * 64 + ni * 16 + c16;
                if (isq)
                    Cq[(size_t)row * 1536 + col] = __float2bfloat16(acc[mi][ni][r]);
                else
                    Ckv[(size_t)row * 384 + col] = acc[mi][ni][r];
            }
}

// ---------------- small batched bf16 MFMA GEMM (64x64 tiles, global_load_lds) -------------
template <typename TC>
__global__ __launch_bounds__(256, 4) void gemm64_lds(const bf16* __restrict__ A, int lda, int aoffz,
                                                     const bf16* __restrict__ Bm, int ldb, int boffz,
                                                     TC* __restrict__ C, int ldc, int coffz,
                                                     int K, float scale) {
    int z = blockIdx.z;
    A += (size_t)z * aoffz;
    Bm += (size_t)z * boffz;
    C += (size_t)z * coffz;
    __shared__ bf16 Asf[64 * 32];
    __shared__ bf16 Bsf[64 * 32];
    int tid = threadIdx.x;
    int lane = tid & 63, w = tid >> 6;
    int q4 = lane >> 4, c16 = lane & 15;
    int m0 = blockIdx.y * 64, n0 = blockIdx.x * 64;
    floatx4 acc[4];
#pragma unroll
    for (int ni = 0; ni < 4; ++ni) acc[ni] = (floatx4){0.f, 0.f, 0.f, 0.f};
    int row = tid >> 2, kc = tid & 3;
    for (int k0 = 0; k0 < K; k0 += 32) {
        __syncthreads();
        g2l16(&A[(size_t)(m0 + row) * lda + k0 + kc * 8], &Asf[tid * 8]);
        g2l16(&Bm[(size_t)(n0 + row) * ldb + k0 + kc * 8], &Bsf[tid * 8]);
        __syncthreads();
        short8 af = *(const short8*)(const void*)&Asf[(w * 16 + c16) * 32 + q4 * 8];
#pragma unroll
        for (int ni = 0; ni < 4; ++ni) {
            short8 bfr = *(const short8*)(const void*)&Bsf[(ni * 16 + c16) * 32 + q4 * 8];
            acc[ni] = __builtin_amdgcn_mfma_f32_16x16x32_bf16(af, bfr, acc[ni], 0, 0, 0);
        }
    }
#pragma unroll
    for (int ni = 0; ni < 4; ++ni)
#pragma unroll
        for (int rr = 0; rr < 4; ++rr)
            store_c(C, (size_t)(m0 + w * 16 + q4 * 4 + rr) * ldc + n0 + ni * 16 + c16,
                    acc[ni][rr] * scale);
}

// ---------------- fused C2/P2 + gates: writes g0/g1 only (no C2/P2 globals) --------------
// Block t computes C2[t], P2[t] AND P2[t-1] rows in-register (P-weights loaded once,
// two FMAs), then wave-reduces both dots -> sigmoid.
__global__ __launch_bounds__(64) void c2p2g_kernel(const float* __restrict__ fcw_c,
                                                   const float* __restrict__ fcb_c,
                                                   const float* __restrict__ fcw_p,
                                                   const float* __restrict__ fcb_p,
                                                   float* __restrict__ g0,
                                                   float* __restrict__ g1) {
    int t = blockIdx.x;
    int k = threadIdx.x;
    __shared__ float Crow[256], Prow[256], Pprev[256];
    for (int i = k; i < 128; i += 64) {
        float div = expf(-(float)i * 0.07195578415606393f);  // ln(1e4)/128
        float ap = (float)t * div;
        Prow[2 * i]     = sinf(ap);
        Prow[2 * i + 1] = cosf(ap);
        float ac = (float)(t >> 1) * div;
        Crow[2 * i]     = sinf(ac);
        Crow[2 * i + 1] = cosf(ac);
        float app = (float)(t - 1) * div;  // unused for even t
        Pprev[2 * i]     = sinf(app);
        Pprev[2 * i + 1] = cosf(app);
    }
    __syncthreads();
    float sc = fcb_c[k], sp = fcb_p[k], spp = fcb_p[k];
    for (int c = 0; c < 256; ++c) {
        float wc_ = fcw_c[(size_t)k * 256 + c];
        float wp_ = fcw_p[(size_t)k * 256 + c];
        sc += Crow[c] * wc_;
        sp += Prow[c] * wp_;
        spp += Pprev[c] * wp_;
    }
    float d0 = sc * sp, d1 = sc * spp;
#pragma unroll
    for (int o = 32; o; o >>= 1) {
        d0 += __shfl_down(d0, o);
        d1 += __shfl_down(d1, o);
    }
    if (k == 0) {
        g0[t] = 1.0f / (1.0f + expf(-d0));
        g1[t] = (t & 1) ? 1.0f / (1.0f + expf(-d1)) : 0.f;
    }
}

// ---------------- fused LayerNorm + RoPE + gated kve (odd/even pair per block) -----------
// Block = (b, u): rows t0=2u, t1=2u+1. Computes both LNs + both k_pe ropes + gated
// combine entirely in registers -> kve_full rows t0,t1 and kvo row u. kv_c/kpe globals
// eliminated (~17 MB of roundtrip traffic + one dispatch).
__global__ __launch_bounds__(256) void lnkve_kernel(const float* __restrict__ kvraw,
                                                    const float* __restrict__ g,
                                                    const float* __restrict__ bta,
                                                    const float* __restrict__ g0,
                                                    const float* __restrict__ g1,
                                                    bf16* __restrict__ kve_full,
                                                    bf16* __restrict__ kvo) {
    int pb = blockIdx.x;
    int b = pb >> 10, u = pb & 1023;
    int t0 = 2 * u, t1 = 2 * u + 1;
    size_t r0 = (size_t)b * S_ + t0, r1 = r0 + 1;
    int tid = threadIdx.x;
    int lane = tid & 63, w = tid >> 6;
    float x0 = kvraw[r0 * 384 + tid];
    float x1 = kvraw[r1 * 384 + tid];
    float s0 = x0, q0 = x0 * x0, s1 = x1, q1 = x1 * x1;
#pragma unroll
    for (int o = 32; o; o >>= 1) {
        s0 += __shfl_down(s0, o); q0 += __shfl_down(q0, o);
        s1 += __shfl_down(s1, o); q1 += __shfl_down(q1, o);
    }
    __shared__ float red[4][4];
    __shared__ float st[4];
    if (lane == 0) { red[w][0] = s0; red[w][1] = q0; red[w][2] = s1; red[w][3] = q1; }
    __syncthreads();
    if (tid == 0) {
        float S0 = red[0][0] + red[1][0] + red[2][0] + red[3][0];
        float Q0 = red[0][1] + red[1][1] + red[2][1] + red[3][1];
        float S1 = red[0][2] + red[1][2] + red[2][2] + red[3][2];
        float Q1 = red[0][3] + red[1][3] + red[2][3] + red[3][3];
        float m0 = S0 / 256.0f, m1 = S1 / 256.0f;
        st[0] = m0; st[1] = rsqrtf(Q0 / 256.0f - m0 * m0 + 1e-5f);
        st[2] = m1; st[3] = rsqrtf(Q1 / 256.0f - m1 * m1 + 1e-5f);
    }
    __syncthreads();
    float gg = g[tid], bb_ = bta[tid];
    float y0 = (x0 - st[0]) * st[1] * gg + bb_;
    float y1 = (x1 - st[2]) * st[3] * gg + bb_;
    float a0 = g0[t0], a1 = g0[t1], b1 = g1[t1];
    kve_full[r0 * 288 + tid] = __float2bfloat16(a0 * y0);
    float vo = a1 * y1 + b1 * y0;
    bf16 vob = __float2bfloat16(vo);
    kve_full[r1 * 288 + tid] = vob;
    kvo[((size_t)b * 1024 + u) * 296 + tid] = vob;
    if (tid < 16) {
        int j = tid;
        float freq = expf(-(float)(2 * j) * 0.28782313662425572f);  // ln(1e4)/32
        float a00 = (float)t0 * freq, a01 = (float)t1 * freq;
        float c0 = cosf(a00), sn0 = sinf(a00);
        float c1 = cosf(a01), sn1 = sinf(a01);
        float e00 = kvraw[r0 * 384 + 256 + 2 * j], e01 = kvraw[r0 * 384 + 256 + 2 * j + 1];
        float e10 = kvraw[r1 * 384 + 256 + 2 * j], e11 = kvraw[r1 * 384 + 256 + 2 * j + 1];
        float k00 = e00 * c0 - e01 * sn0, k01 = e00 * sn0 + e01 * c0;
        float k10 = e10 * c1 - e11 * sn1, k11 = e10 * sn1 + e11 * c1;
        kve_full[r0 * 288 + 256 + 2 * j]     = __float2bfloat16(a0 * k00);
        kve_full[r0 * 288 + 256 + 2 * j + 1] = __float2bfloat16(a0 * k01);
        float u0 = a1 * k10 + b1 * k00, u1 = a1 * k11 + b1 * k01;
        bf16 u0b = __float2bfloat16(u0), u1b = __float2bfloat16(u1);
        kve_full[r1 * 288 + 256 + 2 * j]     = u0b;
        kve_full[r1 * 288 + 256 + 2 * j + 1] = u1b;
        kvo[((size_t)b * 1024 + u) * 296 + 256 + 2 * j]     = u0b;
        kvo[((size_t)b * 1024 + u) * 296 + 256 + 2 * j + 1] = u1b;
    }
}

// ---------------- kvoT32[b][uch][c][chunk] = kvo[b][uch*32 + tau(kslot)][c] --------------
// tau(8q+j) = (j<4) ? 4q+j : 16 + 4q + (j-4); chunks XOR-swizzled (chunk^((c>>1)&3)) so
// linear global_load_lds staging lands conflict-free (HW-verified R4/R5).
__global__ __launch_bounds__(256) void kvoT32_kernel(const bf16* __restrict__ kvo,
                                                     bf16* __restrict__ kvoT) {
    int uch = blockIdx.x, b = blockIdx.y;
    int c = threadIdx.x;
    const bf16* src = kvo + ((size_t)b * 1024 + uch * 32) * 296 + c;
    short v[32];
#pragma unroll
    for (int j = 0; j < 32; ++j) v[j] = *(const short*)&src[(size_t)j * 296];
    bf16* dst = kvoT + (((size_t)b * 32 + uch) * 256 + c) * 32;
    int swz = (c >> 1) & 3;
#pragma unroll
    for (int q = 0; q < 4; ++q) {
        short8 o;
#pragma unroll
        for (int jj = 0; jj < 8; ++jj)
            o[jj] = (jj < 4) ? v[4 * q + jj] : v[16 + 4 * q + (jj - 4)];
        *(short8*)(void*)&dst[(q ^ swz) * 8] = o;
    }
}

// ---------------- roped, scaled q_pe -> qe[...,256:288) ----------------
__global__ __launch_bounds__(256) void rope_qe_kernel(const bf16* __restrict__ q,
                                                      bf16* __restrict__ qe) {
    int idx = blockIdx.x * 256 + threadIdx.x;
    if (idx >= B_ * S_ * H_ * 16) return;
    int j = idx & 15;
    int s = (idx >> 8) & (S_ - 1);
    float freq = expf(-(float)(2 * j) * 0.28782313662425572f);
    float ang = (float)s * freq;
    float c = cosf(ang), sn = sinf(ang);
    size_t row = idx >> 4;
    float a0 = bf2f(q[row * QKD_ + NOPE_ + 2 * j]);
    float a1 = bf2f(q[row * QKD_ + NOPE_ + 2 * j + 1]);
    qe[row * 288 + 256 + 2 * j]     = __float2bfloat16((a0 * c - a1 * sn) * SCALE_);
    qe[row * 288 + 256 + 2 * j + 1] = __float2bfloat16((a0 * sn + a1 * c) * SCALE_);
}

// ---------------- flash attention: 32-key tiles, dbuf, XOR-swizzled PV, fused sscore -----
__global__ __launch_bounds__(256, 2) void attn8_kernel(const bf16* __restrict__ qe,
                                                       const bf16* __restrict__ kvo,
                                                       const bf16* __restrict__ kvoT,
                                                       const bf16* __restrict__ kve_full,
                                                       bf16* __restrict__ xout) {
    int s0 = (int)(gridDim.x - 1 - blockIdx.x) * 4;  // biggest blocks first
    int b = blockIdx.y;
    int tid = threadIdx.x;
    int lane = tid & 63, w = tid >> 6;
    int q4 = lane >> 4, c16 = lane & 15;
    int s = s0 + w;
    int Nodd = (s + 1) >> 1;
    int NoddMax = (s0 + 4) >> 1;
    int niter = (NoddMax + 31) >> 5;

    __shared__ bf16 kvos[2][32][296];   // 2 x 18944 B: score-side K rows
    __shared__ bf16 kvts[2][256][32];   // 2 x 16384 B: PV-side V tile (tau+XOR layout)
    __shared__ bf16 selfr[4][288];      // self-key kv rows, FULL 288 channels

    const bf16* kvob = kvo + (size_t)b * 1024 * 296;
    const bf16* kvoTb = kvoT + (size_t)b * 32 * 8192;

    if (tid < 144) {
        int rr = tid / 36, ch = tid - rr * 36;
        *(short8*)(void*)&selfr[rr][ch * 8] =
            *(const short8*)(const void*)&kve_full[(size_t)(b * S_ + s0 + rr) * 288 + ch * 8];
    }

    short8 qf[9];
    const bf16* qrow = qe + ((size_t)(b * S_ + s) * H_ + c16) * 288;
#pragma unroll
    for (int kk = 0; kk < 9; ++kk) qf[kk] = *(const short8*)(const void*)&qrow[kk * 32 + q4 * 8];

    floatx4 acc[16];
#pragma unroll
    for (int n = 0; n < 16; ++n) acc[n] = (floatx4){0.f, 0.f, 0.f, 0.f};
    float m_i = -1e30f, l_i = 0.f;
    int swz = (c16 >> 1) & 3;  // PV chunk XOR (matches kvoT32 writer)

    auto stage = [&](int t, int p) {
        const bf16* sa = kvob + (size_t)t * 32 * 296;
        bf16* la = &kvos[p][0][0];
#pragma unroll
        for (int i = 0; i < 4; ++i)
            g2l16(&sa[(size_t)(tid + i * 256) * 8], &la[(size_t)(tid + i * 256) * 8]);
        if (tid < 160) g2l16(&sa[(size_t)(tid + 1024) * 8], &la[(size_t)(tid + 1024) * 8]);
        const bf16* sb = kvoTb + (size_t)t * 8192;
        bf16* lb = &kvts[p][0][0];
#pragma unroll
        for (int i = 0; i < 4; ++i)
            g2l16(&sb[(size_t)(tid + i * 256) * 8], &lb[(size_t)(tid + i * 256) * 8]);
    };

    stage(0, 0);
    __syncthreads();  // prologue drain (also makes selfr visible)

    // in-register self score: dot(qe_row(s,h=c16), kve_row(s)); reduce over q4 via shfl.
    float sdot = 0.f;
#pragma unroll
    for (int kk = 0; kk < 9; ++kk) {
        short8 kv8 = *(const short8*)(const void*)&selfr[w][kk * 32 + q4 * 8];
#pragma unroll
        for (int j = 0; j < 8; ++j) sdot += s2f(qf[kk][j]) * s2f(kv8[j]);
    }
    sdot += __shfl_xor(sdot, 16);
    sdot += __shfl_xor(sdot, 32);

    for (int it = 0; it < niter; ++it) {
        int p = it & 1;
        if (it + 1 < niter) stage(it + 1, 1 - p);

        int u0 = it * 32;
        floatx4 ca0 = (floatx4){0.f, 0.f, 0.f, 0.f}, ca1 = (floatx4){0.f, 0.f, 0.f, 0.f};
        floatx4 cb0 = (floatx4){0.f, 0.f, 0.f, 0.f}, cb1 = (floatx4){0.f, 0.f, 0.f, 0.f};
        __builtin_amdgcn_s_setprio(1);
#pragma unroll
        for (int kk = 0; kk < 9; ++kk) {
            short8 avA = *(const short8*)(const void*)&kvos[p][c16][kk * 32 + q4 * 8];
            short8 avB = *(const short8*)(const void*)&kvos[p][16 + c16][kk * 32 + q4 * 8];
            if (kk & 1) {
                ca1 = __builtin_amdgcn_mfma_f32_16x16x32_bf16(avA, qf[kk], ca1, 0, 0, 0);
                cb1 = __builtin_amdgcn_mfma_f32_16x16x32_bf16(avB, qf[kk], cb1, 0, 0, 0);
            } else {
                ca0 = __builtin_amdgcn_mfma_f32_16x16x32_bf16(avA, qf[kk], ca0, 0, 0, 0);
                cb0 = __builtin_amdgcn_mfma_f32_16x16x32_bf16(avB, qf[kk], cb0, 0, 0, 0);
            }
        }
        __builtin_amdgcn_s_setprio(0);
        floatx4 cA = ca0 + ca1;
        floatx4 cB = cb0 + cb1;
        int kA = u0 + q4 * 4;
        int kB = u0 + 16 + q4 * 4;
#pragma unroll
        for (int r = 0; r < 4; ++r) {
            if (kA + r >= Nodd) cA[r] = -1e30f;
            if (kB + r >= Nodd) cB[r] = -1e30f;
        }
        float tmax = fmaxf(fmaxf(fmaxf(cA[0], cA[1]), fmaxf(cA[2], cA[3])),
                           fmaxf(fmaxf(cB[0], cB[1]), fmaxf(cB[2], cB[3])));
        tmax = fmaxf(tmax, __shfl_xor(tmax, 16));
        tmax = fmaxf(tmax, __shfl_xor(tmax, 32));
        float mn = fmaxf(m_i, tmax);
        bool chg = mn > m_i;
        float al = __expf(m_i - mn);
        float pA0 = __expf(cA[0] - mn), pA1 = __expf(cA[1] - mn);
        float pA2 = __expf(cA[2] - mn), pA3 = __expf(cA[3] - mn);
        float pB0 = __expf(cB[0] - mn), pB1 = __expf(cB[1] - mn);
        float pB2 = __expf(cB[2] - mn), pB3 = __expf(cB[3] - mn);
        float rs = (pA0 + pA1 + pA2 + pA3) + (pB0 + pB1 + pB2 + pB3);
        rs += __shfl_xor(rs, 16);
        rs += __shfl_xor(rs, 32);
        l_i = l_i * al + rs;
        m_i = mn;
        if (__any(chg)) {
#pragma unroll
            for (int n = 0; n < 16; ++n) {
                acc[n][0] *= al; acc[n][1] *= al; acc[n][2] *= al; acc[n][3] *= al;
            }
        }
        short8 pf;
        pf[0] = f2bf_s(pA0); pf[1] = f2bf_s(pA1); pf[2] = f2bf_s(pA2); pf[3] = f2bf_s(pA3);
        pf[4] = f2bf_s(pB0); pf[5] = f2bf_s(pB1); pf[6] = f2bf_s(pB2); pf[7] = f2bf_s(pB3);
        __builtin_amdgcn_s_setprio(1);
#pragma unroll
        for (int n = 0; n < 16; ++n) {
            short8 a8 = *(const short8*)(const void*)&kvts[p][n * 16 + c16][(q4 ^ swz) * 8];
            acc[n] = __builtin_amdgcn_mfma_f32_16x16x32_bf16(a8, pf, acc[n], 0, 0, 0);
        }
        __builtin_amdgcn_s_setprio(0);
        __syncthreads();
    }

    if ((s & 1) == 0) {
        float mn = fmaxf(m_i, sdot);
        float al = __expf(m_i - mn);
        float pp = __expf(sdot - mn);
        l_i = l_i * al + pp;
        m_i = mn;
#pragma unroll
        for (int n = 0; n < 16; ++n) {
            short4v kv4 = *(const short4v*)(const void*)&selfr[w][n * 16 + q4 * 4];
#pragma unroll
            for (int r = 0; r < 4; ++r)
                acc[n][r] = acc[n][r] * al + pp * s2f(kv4[r]);
        }
    }

    float invl = 1.0f / l_i;
    bf16* orow = xout + ((size_t)(b * S_ + s) * H_ + c16) * 256;
#pragma unroll
    for (int n = 0; n < 16; ++n) {
        short4v o;
        o[0] = f2bf_s(acc[n][0] * invl);
        o[1] = f2bf_s(acc[n][1] * invl);
        o[2] = f2bf_s(acc[n][2] * invl);
        o[3] = f2bf_s(acc[n][3] * invl);
        *(short4v*)(void*)&orow[n * 16 + q4 * 4] = o;
    }
}

extern "C" void kernel_launch(void* const* d_in, const int* in_sizes, int n_in,
                              void* d_out, int out_size, void* d_ws, size_t ws_size,
                              hipStream_t stream) {
    const float* hs     = (const float*)d_in[0];
    const float* wq     = (const float*)d_in[1];
    const float* wkv_a  = (const float*)d_in[2];
    const float* ln_g   = (const float*)d_in[3];
    const float* ln_b   = (const float*)d_in[4];
    const float* wkv_b  = (const float*)d_in[5];
    const float* wo     = (const float*)d_in[6];
    const float* fc_c_w = (const float*)d_in[7];
    const float* fc_c_b = (const float*)d_in[8];
    const float* fc_p_w = (const float*)d_in[9];
    const float* fc_p_b = (const float*)d_in[10];
    float* out = (float*)d_out;
    (void)in_sizes; (void)n_in; (void)out_size; (void)ws_size;

    const int M = B_ * S_;  // 4096
    char* wsb = (char*)d_ws;
    size_t o = 0;
    auto alloc = [&](size_t bytes) { char* p = wsb + o; o += (bytes + 255) & ~(size_t)255; return p; };

    bf16* qe = (bf16*)alloc((size_t)M * H_ * 288 * 2);  // 37.75 MB
    char* region2 = alloc((size_t)M * H_ * 256 * 2);    // 33.55 MB
    bf16* hs_bf    = (bf16*)region2;
    bf16* wq_bf    = (bf16*)(region2 + (size_t)M * E_ * 2);
    bf16* wkva_pad = (bf16*)(region2 + (size_t)M * E_ * 2 + (size_t)1536 * E_ * 2);
    bf16* x_bf     = (bf16*)region2;
    char* region3 = alloc((size_t)M * 1536 * 2);        // 12.58 MB
    bf16* q_bf    = (bf16*)region3;
    bf16* outp_bf = (bf16*)region3;
    float* kvraw = (float*)alloc((size_t)M * 384 * 4);
    bf16* wo_bf   = (bf16*)alloc((size_t)E_ * 1024 * 2);
    bf16* wkvb_bf = (bf16*)alloc((size_t)2048 * 256 * 2);
    bf16* wkvbT   = (bf16*)alloc((size_t)H_ * 256 * 64 * 2);
    bf16* kve_full = (bf16*)alloc((size_t)M * 288 * 2);
    bf16* kvo      = (bf16*)alloc((size_t)B_ * 1024 * 296 * 2);
    bf16* kvoT     = (bf16*)alloc((size_t)B_ * 32 * 8192 * 2);
    float* g0 = (float*)alloc(S_ * 4);
    float* g1 = (float*)alloc(S_ * 4);

    // fused conversions + wkvbT transpose — one launch
    conv_fused_kernel<<<(CV_N5 + 255) / 256, 256, 0, stream>>>(
        hs, wq, wo, wkv_b, wkv_a, hs_bf, wq_bf, wo_bf, wkvb_bf, wkva_pad, wkvbT);
    // fused projections: q (bf16) + kvraw (f32), 64x128 tiles, 960 blocks, XCD swizzle
    gemm_qkv_fused64<<<960, 256, 0, stream>>>(hs_bf, wq_bf, wkva_pad, q_bf, kvraw, E_);
    // gates (C2/P2 fused in)
    c2p2g_kernel<<<S_, 64, 0, stream>>>(fc_c_w, fc_c_b, fc_p_w, fc_p_b, g0, g1);
    // LN + rope + gated kve (pair-block; kv_c/kpe eliminated)
    lnkve_kernel<<<B_ * 1024, 256, 0, stream>>>(kvraw, ln_g, ln_b, g0, g1, kve_full, kvo);
    kvoT32_kernel<<<dim3(32, B_), 256, 0, stream>>>(kvo, kvoT);
    // qe = [q_abs * SCALE | rope(q_pe) * SCALE]
    gemm64_lds<bf16><<<dim3(256 / 64, M / 64, H_), 256, 0, stream>>>(
        q_bf, H_ * QKD_, QKD_, wkvbT, 64, 256 * 64, qe, H_ * 288, 288, 64, SCALE_);
    rope_qe_kernel<<<(M * H_ * 16 + 255) / 256, 256, 0, stream>>>(q_bf, qe);
    // attention (32-key tiles, dbuf, XOR-deconflicted PV, fused self-score)
    attn8_kernel<<<dim3(S_ / 4, B_), 256, 0, stream>>>(qe, kvo, kvoT, kve_full, x_bf);
    // V-projection per head
    gemm64_lds<bf16><<<dim3(1, M / 64, H_), 256, 0, stream>>>(
        x_bf, H_ * 256, 256, wkvb_bf + (size_t)64 * 256, 256, 128 * 256, outp_bf, 1024, 64, 256, 1.0f);
    // final out = outp @ wo^T
    gemm_bt_lds<float><<<dim3(E_ / 128, M / 128), 256, 0, stream>>>(outp_bf, wo_bf, out, M, E_, 1024);
}